// Round 1
// baseline (1151.282 us; speedup 1.0000x reference)
//
#include <hip/hip_runtime.h>
#include <cstdint>
#include <cstddef>

// Problem constants (from reference)
static const int NN = 100000;
static const int NE = 1600000;
static const int F  = 128;       // hidden / input feature width
static const int CHUNK = 1024;   // scan chunk

// ---------------- CSR build ----------------

__global__ void hist_k(const int* __restrict__ dst, int* __restrict__ counts, int E){
    int e = blockIdx.x*256 + threadIdx.x;
    if (e < E) atomicAdd(&counts[dst[e]], 1);
}

__global__ void chunk_sum_k(const int* __restrict__ counts, int* __restrict__ bsum, int N){
    __shared__ int sm[256];
    int base = blockIdx.x*CHUNK;
    int t = threadIdx.x;
    int s = 0;
    #pragma unroll
    for (int j = 0; j < 4; ++j){
        int idx = base + j*256 + t;
        s += (idx < N) ? counts[idx] : 0;
    }
    sm[t] = s; __syncthreads();
    for (int off = 128; off > 0; off >>= 1){
        if (t < off) sm[t] += sm[t+off];
        __syncthreads();
    }
    if (t == 0) bsum[blockIdx.x] = sm[0];
}

__global__ void scan_small_k(int* __restrict__ bsum, int nb){
    if (blockIdx.x == 0 && threadIdx.x == 0){
        int run = 0;
        for (int i = 0; i < nb; ++i){ int v = bsum[i]; bsum[i] = run; run += v; }
    }
}

__global__ void chunk_scan_k(const int* __restrict__ counts, const int* __restrict__ bsum,
                             int* __restrict__ row_ptr, int N, int E){
    __shared__ int sm[256];
    int base = blockIdx.x*CHUNK;
    int t = threadIdx.x;
    int v[4]; int s = 0;
    #pragma unroll
    for (int j = 0; j < 4; ++j){
        int idx = base + t*4 + j;
        int c = (idx < N) ? counts[idx] : 0;
        v[j] = s; s += c;
    }
    sm[t] = s; __syncthreads();
    // inclusive Hillis-Steele scan over 256 thread partials
    for (int off = 1; off < 256; off <<= 1){
        int add = (t >= off) ? sm[t-off] : 0;
        __syncthreads();
        sm[t] += add;
        __syncthreads();
    }
    int texcl = sm[t] - s;           // exclusive offset of this thread in chunk
    int co = bsum[blockIdx.x];       // exclusive offset of this chunk
    #pragma unroll
    for (int j = 0; j < 4; ++j){
        int idx = base + t*4 + j;
        if (idx < N) row_ptr[idx] = co + texcl + v[j];
    }
    if (base == 0 && t == 0) row_ptr[N] = E;
}

__global__ void scatter_k(const int* __restrict__ src, const int* __restrict__ dst,
                          const int* __restrict__ row_ptr, int* __restrict__ fill,
                          int* __restrict__ src_sorted, int E){
    int e = blockIdx.x*256 + threadIdx.x;
    if (e < E){
        int d = dst[e];
        int p = atomicAdd(&fill[d], 1);
        src_sorted[row_ptr[d] + p] = src[e];
    }
}

// ---------------- dual GEMM: Y = h@Ws + b ; Z = h@Wn ----------------
// Tile: 64 nodes x D cols, block = 256 threads.
// thread t: cols {t&63, (t&63)+64}; nodes (t>>6)*16 .. +15.

__global__ __launch_bounds__(256) void gemm2_k(const float* __restrict__ h,
        const float* __restrict__ Ws, const float* __restrict__ Wn,
        const float* __restrict__ bias,
        float* __restrict__ Y, float* __restrict__ Z, int N, int D){
    __shared__ float hl[64*128];
    const int tile = blockIdx.x*64;
    const int t = threadIdx.x;
    const int nrows = min(64, N - tile);
    // coalesced float4 stage of the h tile (node rows are contiguous)
    const float4* s4 = (const float4*)(h + (size_t)tile*F);
    float4* d4 = (float4*)hl;
    for (int i = t; i < nrows*(F/4); i += 256) d4[i] = s4[i];
    __syncthreads();

    const int c0 = t & 63;
    const int ng = t >> 6;
    const int c1 = c0 + 64;
    const bool c0ok = (c0 < D);
    const bool c1ok = (c1 < D);

    for (int mat = 0; mat < 2; ++mat){
        const float* __restrict__ W = mat ? Wn : Ws;
        float acc0[16], acc1[16];
        #pragma unroll
        for (int i = 0; i < 16; ++i){ acc0[i] = 0.f; acc1[i] = 0.f; }
        for (int k = 0; k < F; k += 4){
            float w0[4], w1[4];
            #pragma unroll
            for (int j = 0; j < 4; ++j){
                w0[j] = c0ok ? W[(k+j)*D + c0] : 0.f;
                w1[j] = c1ok ? W[(k+j)*D + c1] : 0.f;
            }
            #pragma unroll
            for (int i = 0; i < 16; ++i){
                const float4 hv = *(const float4*)&hl[(ng*16+i)*F + k];
                acc0[i] += hv.x*w0[0] + hv.y*w0[1] + hv.z*w0[2] + hv.w*w0[3];
                acc1[i] += hv.x*w1[0] + hv.y*w1[1] + hv.z*w1[2] + hv.w*w1[3];
            }
        }
        float* __restrict__ O = mat ? Z : Y;
        float bb0 = (!mat && c0ok) ? bias[c0] : 0.f;
        float bb1 = (!mat && c1ok) ? bias[c1] : 0.f;
        #pragma unroll
        for (int i = 0; i < 16; ++i){
            int n = ng*16 + i;
            if (n < nrows){
                size_t rowo = (size_t)(tile + n)*D;
                if (c0ok) O[rowo + c0] = acc0[i] + bb0;
                if (c1ok) O[rowo + c1] = acc1[i] + bb1;
            }
        }
    }
}

// ---------------- aggregation: out = Y + (sum Z[src])/deg, optional relu ----------------
// one 64-lane wave per node; 4 waves per block

__global__ __launch_bounds__(256) void agg_k(const float* __restrict__ Yb, const float* __restrict__ Zb,
        const int* __restrict__ row_ptr, const int* __restrict__ src_sorted,
        float* __restrict__ out, int N, int D, int relu){
    const int lane = threadIdx.x & 63;
    const int node = blockIdx.x*4 + (threadIdx.x >> 6);
    if (node >= N) return;
    const int beg = row_ptr[node], end = row_ptr[node+1];
    const float inv = 1.0f / fmaxf((float)(end - beg), 1.0f);
    if (D == 128){
        float a0 = 0.f, a1 = 0.f;
        for (int e = beg; e < end; ++e){
            const float* zp = Zb + (size_t)src_sorted[e]*128;
            a0 += zp[lane];
            a1 += zp[lane+64];
        }
        size_t o = (size_t)node*128;
        float r0 = Yb[o+lane]    + a0*inv;
        float r1 = Yb[o+lane+64] + a1*inv;
        if (relu){ r0 = fmaxf(r0, 0.f); r1 = fmaxf(r1, 0.f); }
        out[o+lane]    = r0;
        out[o+lane+64] = r1;
    } else {
        float a0 = 0.f;
        for (int e = beg; e < end; ++e){
            int s = src_sorted[e];
            a0 += (lane < D) ? Zb[(size_t)s*D + lane] : 0.f;
        }
        if (lane < D){
            float r = Yb[(size_t)node*D + lane] + a0*inv;
            if (relu) r = fmaxf(r, 0.f);
            out[(size_t)node*D + lane] = r;
        }
    }
}

// ---------------- launch ----------------

extern "C" void kernel_launch(void* const* d_in, const int* in_sizes, int n_in,
                              void* d_out, int out_size, void* d_ws, size_t ws_size,
                              hipStream_t stream){
    const float* x   = (const float*)d_in[0];
    const int*   src = (const int*)  d_in[1];
    const int*   dstv= (const int*)  d_in[2];
    const float* Ws0 = (const float*)d_in[3];
    const float* Wn0 = (const float*)d_in[4];
    const float* b0  = (const float*)d_in[5];
    const float* Ws1 = (const float*)d_in[6];
    const float* Wn1 = (const float*)d_in[7];
    const float* b1  = (const float*)d_in[8];
    const float* Ws2 = (const float*)d_in[9];
    const float* Wn2 = (const float*)d_in[10];
    const float* b2  = (const float*)d_in[11];
    float* out = (float*)d_out;
    const int N = NN, E = NE;

    char* w = (char*)d_ws;
    size_t off = 0;
    auto alloc = [&](size_t bytes)->char*{
        char* p = w + off; off += (bytes + 255) & ~(size_t)255; return p;
    };
    int*   counts  = (int*)  alloc((size_t)N*4);
    int*   row_ptr = (int*)  alloc((size_t)(N+1)*4);
    int*   ssorted = (int*)  alloc((size_t)E*4);
    int*   bsum    = (int*)  alloc(4096);
    float* bufA    = (float*)alloc((size_t)N*F*4);
    float* bufB    = (float*)alloc((size_t)N*F*4);
    float* bufZ    = (float*)alloc((size_t)N*F*4);
    (void)ws_size; (void)n_in; (void)in_sizes; (void)out_size;

    const int NB = (N + CHUNK - 1)/CHUNK;

    hipMemsetAsync(counts, 0, (size_t)N*4, stream);
    hist_k      <<<(E+255)/256, 256, 0, stream>>>(dstv, counts, E);
    chunk_sum_k <<<NB, 256, 0, stream>>>(counts, bsum, N);
    scan_small_k<<<1, 64, 0, stream>>>(bsum, NB);
    chunk_scan_k<<<NB, 256, 0, stream>>>(counts, bsum, row_ptr, N, E);
    hipMemsetAsync(counts, 0, (size_t)N*4, stream);
    scatter_k   <<<(E+255)/256, 256, 0, stream>>>(src, dstv, row_ptr, counts, ssorted, E);

    const int GT = (N + 63)/64;
    const int GA = (N + 3)/4;

    // layer 0: x -> bufA
    gemm2_k<<<GT, 256, 0, stream>>>(x,    Ws0, Wn0, b0, bufA, bufZ, N, 128);
    agg_k  <<<GA, 256, 0, stream>>>(bufA, bufZ, row_ptr, ssorted, bufA, N, 128, 1);
    // layer 1: bufA -> bufB
    gemm2_k<<<GT, 256, 0, stream>>>(bufA, Ws1, Wn1, b1, bufB, bufZ, N, 128);
    agg_k  <<<GA, 256, 0, stream>>>(bufB, bufZ, row_ptr, ssorted, bufB, N, 128, 1);
    // layer 2: bufB -> out (D=47, no relu)
    gemm2_k<<<GT, 256, 0, stream>>>(bufB, Ws2, Wn2, b2, out, bufZ, N, 47);
    agg_k  <<<GA, 256, 0, stream>>>(out,  bufZ, row_ptr, ssorted, out, N, 47, 0);
}

// Round 2
// 785.700 us; speedup vs baseline: 1.4653x; 1.4653x over previous
//
#include <hip/hip_runtime.h>
#include <cstdint>
#include <cstddef>

static const int NN = 100000;
static const int NE = 1600000;
static const int F  = 128;       // K dim (feature width)
static const int CHUNK = 1024;   // scan chunk

typedef __attribute__((ext_vector_type(8))) short short8;
typedef __attribute__((ext_vector_type(4))) float float4v;

static __device__ __forceinline__ unsigned short f2bf(float f){
    unsigned u = __builtin_bit_cast(unsigned, f);
    unsigned r = (u + 0x7FFFu + ((u >> 16) & 1u)) >> 16;
    return (unsigned short)r;
}
static __device__ __forceinline__ float bf_lo(unsigned u){
    return __builtin_bit_cast(float, u << 16);
}
static __device__ __forceinline__ float bf_hi(unsigned u){
    return __builtin_bit_cast(float, u & 0xFFFF0000u);
}

// ---------------- CSR build ----------------

__global__ void hist_k(const int* __restrict__ dst, int* __restrict__ counts, int E){
    int e = blockIdx.x*256 + threadIdx.x;
    if (e < E) atomicAdd(&counts[dst[e]], 1);
}

__global__ void chunk_sum_k(const int* __restrict__ counts, int* __restrict__ bsum, int N){
    __shared__ int sm[256];
    int base = blockIdx.x*CHUNK;
    int t = threadIdx.x;
    int s = 0;
    #pragma unroll
    for (int j = 0; j < 4; ++j){
        int idx = base + j*256 + t;
        s += (idx < N) ? counts[idx] : 0;
    }
    sm[t] = s; __syncthreads();
    for (int off = 128; off > 0; off >>= 1){
        if (t < off) sm[t] += sm[t+off];
        __syncthreads();
    }
    if (t == 0) bsum[blockIdx.x] = sm[0];
}

__global__ void scan_small_k(int* __restrict__ bsum, int nb){
    if (blockIdx.x == 0 && threadIdx.x == 0){
        int run = 0;
        for (int i = 0; i < nb; ++i){ int v = bsum[i]; bsum[i] = run; run += v; }
    }
}

__global__ void chunk_scan_k(const int* __restrict__ counts, const int* __restrict__ bsum,
                             int* __restrict__ row_ptr, int N, int E){
    __shared__ int sm[256];
    int base = blockIdx.x*CHUNK;
    int t = threadIdx.x;
    int v[4]; int s = 0;
    #pragma unroll
    for (int j = 0; j < 4; ++j){
        int idx = base + t*4 + j;
        int c = (idx < N) ? counts[idx] : 0;
        v[j] = s; s += c;
    }
    sm[t] = s; __syncthreads();
    for (int off = 1; off < 256; off <<= 1){
        int add = (t >= off) ? sm[t-off] : 0;
        __syncthreads();
        sm[t] += add;
        __syncthreads();
    }
    int texcl = sm[t] - s;
    int co = bsum[blockIdx.x];
    #pragma unroll
    for (int j = 0; j < 4; ++j){
        int idx = base + t*4 + j;
        if (idx < N) row_ptr[idx] = co + texcl + v[j];
    }
    if (base == 0 && t == 0) row_ptr[N] = E;
}

__global__ void scatter_k(const int* __restrict__ src, const int* __restrict__ dst,
                          const int* __restrict__ row_ptr, int* __restrict__ fill,
                          int* __restrict__ src_sorted, int E){
    int e = blockIdx.x*256 + threadIdx.x;
    if (e < E){
        int d = dst[e];
        int p = atomicAdd(&fill[d], 1);
        src_sorted[row_ptr[d] + p] = src[e];
    }
}

// ---------------- conversions ----------------

// x f32 -> bf16, 4 elems/thread
__global__ void xconv_k(const float* __restrict__ x, unsigned short* __restrict__ xb, int n4){
    int i = blockIdx.x*256 + threadIdx.x;
    if (i < n4){
        const float4* p = (const float4*)x + i;
        float4 v = *p;
        unsigned short o0 = f2bf(v.x), o1 = f2bf(v.y), o2 = f2bf(v.z), o3 = f2bf(v.w);
        unsigned pack0 = (unsigned)o0 | ((unsigned)o1 << 16);
        unsigned pack1 = (unsigned)o2 | ((unsigned)o3 << 16);
        ((unsigned*)xb)[i*2]   = pack0;
        ((unsigned*)xb)[i*2+1] = pack1;
    }
}

// Ws[k][n],Wn[k][n] f32 -> combined transposed bf16 Wt[n][k], n in [0,Npad)
__global__ void prepw_k(const float* __restrict__ Ws, const float* __restrict__ Wn,
                        unsigned short* __restrict__ Wt, int D, int Npad){
    int i = blockIdx.x*256 + threadIdx.x;   // i = n*128 + k
    int n = i >> 7, k = i & 127;
    if (n < Npad){
        float v = 0.f;
        if (n < D)           v = Ws[k*D + n];
        else if (n < 2*D)    v = Wn[k*D + (n - D)];
        Wt[n*128 + k] = f2bf(v);
    }
}

// ---------------- MFMA GEMM ----------------
// C[M x 128cols_per_blockY] = h[M x 128] @ Wt^T ; Wt is [Npad][128] bf16 (n-major).
// Block: 256 thr = 4 waves (2M x 2N of 64x64). Tile BM=128, BN=128.
// A staged in LDS (32KB) via global_load_lds w/ XOR chunk swizzle.
// B fragments held in registers (read once from global, L2-resident).

__global__ __launch_bounds__(256) void gemm_mfma_k(
        const unsigned short* __restrict__ hb,   // [M][128] bf16
        const unsigned short* __restrict__ Wt,   // [Npad][128] bf16
        const float* __restrict__ bias,
        unsigned short* __restrict__ Y,          // [M][Dpad] bf16
        unsigned short* __restrict__ Z,          // [M][Dpad] bf16
        int M, int D, int Dpad){
    __shared__ char ldsA[128*256];               // 128 rows x 256B, swizzled chunks
    const int t = threadIdx.x;
    const int lane = t & 63;
    const int w = t >> 6;                        // wave id
    const int wm = w >> 1, wn = w & 1;           // 2x2 wave grid
    const int tile = blockIdx.x * 128;
    const int cbase = blockIdx.y * 128;          // global col base

    // ---- stage A tile: rows tile..tile+127, swizzled source ----
    #pragma unroll
    for (int i = 0; i < 8; ++i){
        int chunkid = i*4 + w;                   // 1024B chunk, uniform in wave
        int lin = chunkid*64 + lane;             // 16B slot index
        int row = lin >> 4;
        int cs  = lin & 15;
        int grow = tile + row; if (grow >= M) grow = M - 1;
        const char* src = (const char*)hb + (size_t)grow*256 + ((size_t)(cs ^ (row & 7)) << 4);
        __builtin_amdgcn_global_load_lds(
            (const __attribute__((address_space(1))) void*)src,
            (__attribute__((address_space(3))) void*)(ldsA + (size_t)chunkid*1024 + (size_t)lane*16),
            16, 0, 0);
    }

    // ---- B fragments to registers: wave's 64 cols x K=128 ----
    short8 bfrag[4][4];                          // [nfrag][kk]
    {
        int ncol = cbase + wn*64;                // this wave's col base (row in Wt)
        #pragma unroll
        for (int n = 0; n < 4; ++n){
            int wrow = ncol + n*16 + (lane & 15);
            const unsigned short* bp = Wt + (size_t)wrow*128 + ((lane >> 4) * 8);
            #pragma unroll
            for (int kk = 0; kk < 4; ++kk)
                bfrag[n][kk] = *(const short8*)(bp + kk*32);
        }
    }

    float4v acc[4][4];
    #pragma unroll
    for (int m = 0; m < 4; ++m)
        #pragma unroll
        for (int n = 0; n < 4; ++n)
            acc[m][n] = (float4v){0.f,0.f,0.f,0.f};

    __syncthreads();                             // drains global_load_lds

    // ---- compute ----
    #pragma unroll
    for (int m = 0; m < 4; ++m){
        int r = wm*64 + m*16 + (lane & 15);      // LDS row
        #pragma unroll
        for (int kk = 0; kk < 4; ++kk){
            int c = kk*4 + (lane >> 4);          // 16B chunk within row
            short8 a = *(const short8*)(ldsA + (size_t)r*256 + ((size_t)(c ^ (r & 7)) << 4));
            #pragma unroll
            for (int n = 0; n < 4; ++n)
                acc[m][n] = __builtin_amdgcn_mfma_f32_16x16x32_bf16(a, bfrag[n][kk], acc[m][n], 0, 0, 0);
        }
    }

    // ---- epilogue: split cols into Y (+bias) / Z, store bf16 ----
    #pragma unroll
    for (int m = 0; m < 4; ++m){
        #pragma unroll
        for (int n = 0; n < 4; ++n){
            int c = cbase + wn*64 + n*16 + (lane & 15);
            #pragma unroll
            for (int j = 0; j < 4; ++j){
                int r = tile + wm*64 + m*16 + (lane >> 4)*4 + j;
                if (r < M){
                    float v = acc[m][n][j];
                    if (c < D){
                        v += bias[c];
                        Y[(size_t)r*Dpad + c] = f2bf(v);
                    } else if (c < 2*D){
                        Z[(size_t)r*Dpad + (c - D)] = f2bf(v);
                    }
                }
            }
        }
    }
}

// ---------------- aggregation ----------------
// out = Y + mean(Z[src]) , optional relu. bf16 in, bf16 out. D=128.
// one wave per node, lane handles feats {2l, 2l+1}

__global__ __launch_bounds__(256) void agg128_k(
        const unsigned short* __restrict__ Yb, const unsigned short* __restrict__ Zb,
        const int* __restrict__ row_ptr, const int* __restrict__ ssorted,
        unsigned short* __restrict__ hout, int N){
    const int lane = threadIdx.x & 63;
    const int node = blockIdx.x*4 + (threadIdx.x >> 6);
    if (node >= N) return;
    const int beg = row_ptr[node], end = row_ptr[node+1];
    const float inv = 1.0f / fmaxf((float)(end - beg), 1.0f);
    float a0 = 0.f, a1 = 0.f;
    for (int e = beg; e < end; ++e){
        int s = ssorted[e];
        unsigned u = *(const unsigned*)(Zb + (size_t)s*128 + 2*lane);
        a0 += bf_lo(u);
        a1 += bf_hi(u);
    }
    unsigned yu = *(const unsigned*)(Yb + (size_t)node*128 + 2*lane);
    float r0 = bf_lo(yu) + a0*inv;
    float r1 = bf_hi(yu) + a1*inv;
    r0 = fmaxf(r0, 0.f); r1 = fmaxf(r1, 0.f);
    unsigned o = (unsigned)f2bf(r0) | ((unsigned)f2bf(r1) << 16);
    *(unsigned*)(hout + (size_t)node*128 + 2*lane) = o;
}

// final layer: D=47, Dpad=48, f32 out, no relu
__global__ __launch_bounds__(256) void aggfin_k(
        const unsigned short* __restrict__ Yb, const unsigned short* __restrict__ Zb,
        const int* __restrict__ row_ptr, const int* __restrict__ ssorted,
        float* __restrict__ out, int N){
    const int lane = threadIdx.x & 63;
    const int node = blockIdx.x*4 + (threadIdx.x >> 6);
    if (node >= N) return;
    if (lane >= 24) return;
    const int beg = row_ptr[node], end = row_ptr[node+1];
    const float inv = 1.0f / fmaxf((float)(end - beg), 1.0f);
    float a0 = 0.f, a1 = 0.f;
    for (int e = beg; e < end; ++e){
        int s = ssorted[e];
        unsigned u = *(const unsigned*)(Zb + (size_t)s*48 + 2*lane);
        a0 += bf_lo(u);
        a1 += bf_hi(u);
    }
    unsigned yu = *(const unsigned*)(Yb + (size_t)node*48 + 2*lane);
    int f0 = 2*lane, f1 = 2*lane + 1;
    float r0 = bf_lo(yu) + a0*inv;
    float r1 = bf_hi(yu) + a1*inv;
    out[(size_t)node*47 + f0] = r0;
    if (f1 < 47) out[(size_t)node*47 + f1] = r1;
}

// ---------------- launch ----------------

extern "C" void kernel_launch(void* const* d_in, const int* in_sizes, int n_in,
                              void* d_out, int out_size, void* d_ws, size_t ws_size,
                              hipStream_t stream){
    const float* x   = (const float*)d_in[0];
    const int*   src = (const int*)  d_in[1];
    const int*   dstv= (const int*)  d_in[2];
    const float* Ws0 = (const float*)d_in[3];
    const float* Wn0 = (const float*)d_in[4];
    const float* b0  = (const float*)d_in[5];
    const float* Ws1 = (const float*)d_in[6];
    const float* Wn1 = (const float*)d_in[7];
    const float* b1  = (const float*)d_in[8];
    const float* Ws2 = (const float*)d_in[9];
    const float* Wn2 = (const float*)d_in[10];
    const float* b2  = (const float*)d_in[11];
    float* out = (float*)d_out;
    const int N = NN, E = NE;

    char* w = (char*)d_ws;
    size_t off = 0;
    auto alloc = [&](size_t bytes)->char*{
        char* p = w + off; off += (bytes + 255) & ~(size_t)255; return p;
    };
    int*   counts  = (int*)  alloc((size_t)N*4);
    int*   row_ptr = (int*)  alloc((size_t)(N+1)*4);
    int*   ssorted = (int*)  alloc((size_t)E*4);
    int*   bsum    = (int*)  alloc(4096);
    unsigned short* xb  = (unsigned short*)alloc((size_t)N*F*2);
    unsigned short* hA  = (unsigned short*)alloc((size_t)N*F*2);
    unsigned short* hB  = (unsigned short*)alloc((size_t)N*F*2);
    unsigned short* Yb  = (unsigned short*)alloc((size_t)N*F*2);
    unsigned short* Zb  = (unsigned short*)alloc((size_t)N*F*2);
    unsigned short* Wt0 = (unsigned short*)alloc((size_t)256*128*2);
    unsigned short* Wt1 = (unsigned short*)alloc((size_t)256*128*2);
    unsigned short* Wt2 = (unsigned short*)alloc((size_t)128*128*2);
    (void)ws_size; (void)n_in; (void)in_sizes; (void)out_size;

    const int NB = (N + CHUNK - 1)/CHUNK;

    hipMemsetAsync(counts, 0, (size_t)N*4, stream);
    hist_k      <<<(E+255)/256, 256, 0, stream>>>(dstv, counts, E);
    chunk_sum_k <<<NB, 256, 0, stream>>>(counts, bsum, N);
    scan_small_k<<<1, 64, 0, stream>>>(bsum, NB);
    chunk_scan_k<<<NB, 256, 0, stream>>>(counts, bsum, row_ptr, N, E);
    hipMemsetAsync(counts, 0, (size_t)N*4, stream);
    scatter_k   <<<(E+255)/256, 256, 0, stream>>>(src, dstv, row_ptr, counts, ssorted, E);

    // conversions / weight prep
    xconv_k<<<(N*F/4 + 255)/256, 256, 0, stream>>>(x, xb, N*F/4);
    prepw_k<<<(256*128 + 255)/256, 256, 0, stream>>>(Ws0, Wn0, Wt0, 128, 256);
    prepw_k<<<(256*128 + 255)/256, 256, 0, stream>>>(Ws1, Wn1, Wt1, 128, 256);
    prepw_k<<<(128*128 + 255)/256, 256, 0, stream>>>(Ws2, Wn2, Wt2, 47, 128);

    const int GM = (N + 127)/128;
    const int GA = (N + 3)/4;

    // layer 0
    gemm_mfma_k<<<dim3(GM,2), 256, 0, stream>>>(xb, Wt0, b0, Yb, Zb, N, 128, 128);
    agg128_k   <<<GA, 256, 0, stream>>>(Yb, Zb, row_ptr, ssorted, hA, N);
    // layer 1
    gemm_mfma_k<<<dim3(GM,2), 256, 0, stream>>>(hA, Wt1, b1, Yb, Zb, N, 128, 128);
    agg128_k   <<<GA, 256, 0, stream>>>(Yb, Zb, row_ptr, ssorted, hB, N);
    // layer 2 (D=47, Dpad=48)
    gemm_mfma_k<<<dim3(GM,1), 256, 0, stream>>>(hB, Wt2, b2, Yb, Zb, N, 47, 48);
    aggfin_k   <<<GA, 256, 0, stream>>>(Yb, Zb, row_ptr, ssorted, out, N);
}

// Round 3
// 566.665 us; speedup vs baseline: 2.0317x; 1.3865x over previous
//
#include <hip/hip_runtime.h>
#include <cstdint>
#include <cstddef>

static const int NN = 100000;
static const int NE = 1600000;
static const int F  = 128;       // K dim (feature width)
static const int CHUNK = 1024;   // scan chunk

typedef __attribute__((ext_vector_type(8))) short short8;
typedef __attribute__((ext_vector_type(4))) float float4v;

static __device__ __forceinline__ unsigned short f2bf(float f){
    unsigned u = __builtin_bit_cast(unsigned, f);
    unsigned r = (u + 0x7FFFu + ((u >> 16) & 1u)) >> 16;
    return (unsigned short)r;
}
static __device__ __forceinline__ float bf_lo(unsigned u){
    return __builtin_bit_cast(float, u << 16);
}
static __device__ __forceinline__ float bf_hi(unsigned u){
    return __builtin_bit_cast(float, u & 0xFFFF0000u);
}

// ---------------- CSR build ----------------

__global__ void hist_k(const int* __restrict__ dst, int* __restrict__ counts, int E){
    int e = blockIdx.x*256 + threadIdx.x;
    if (e < E) atomicAdd(&counts[dst[e]], 1);
}

__global__ void chunk_sum_k(const int* __restrict__ counts, int* __restrict__ bsum, int N){
    __shared__ int sm[256];
    int base = blockIdx.x*CHUNK;
    int t = threadIdx.x;
    int s = 0;
    #pragma unroll
    for (int j = 0; j < 4; ++j){
        int idx = base + j*256 + t;
        s += (idx < N) ? counts[idx] : 0;
    }
    sm[t] = s; __syncthreads();
    for (int off = 128; off > 0; off >>= 1){
        if (t < off) sm[t] += sm[t+off];
        __syncthreads();
    }
    if (t == 0) bsum[blockIdx.x] = sm[0];
}

__global__ void scan_small_k(int* __restrict__ bsum, int nb){
    if (blockIdx.x == 0 && threadIdx.x == 0){
        int run = 0;
        for (int i = 0; i < nb; ++i){ int v = bsum[i]; bsum[i] = run; run += v; }
    }
}

__global__ void chunk_scan_k(const int* __restrict__ counts, const int* __restrict__ bsum,
                             int* __restrict__ row_ptr, int N, int E){
    __shared__ int sm[256];
    int base = blockIdx.x*CHUNK;
    int t = threadIdx.x;
    int v[4]; int s = 0;
    #pragma unroll
    for (int j = 0; j < 4; ++j){
        int idx = base + t*4 + j;
        int c = (idx < N) ? counts[idx] : 0;
        v[j] = s; s += c;
    }
    sm[t] = s; __syncthreads();
    for (int off = 1; off < 256; off <<= 1){
        int add = (t >= off) ? sm[t-off] : 0;
        __syncthreads();
        sm[t] += add;
        __syncthreads();
    }
    int texcl = sm[t] - s;
    int co = bsum[blockIdx.x];
    #pragma unroll
    for (int j = 0; j < 4; ++j){
        int idx = base + t*4 + j;
        if (idx < N) row_ptr[idx] = co + texcl + v[j];
    }
    if (base == 0 && t == 0) row_ptr[N] = E;
}

__global__ void scatter_k(const int* __restrict__ src, const int* __restrict__ dst,
                          const int* __restrict__ row_ptr, int* __restrict__ fill,
                          int* __restrict__ src_sorted, int E){
    int e = blockIdx.x*256 + threadIdx.x;
    if (e < E){
        int d = dst[e];
        int p = atomicAdd(&fill[d], 1);
        src_sorted[row_ptr[d] + p] = src[e];
    }
}

// ---------------- conversions ----------------

__global__ void xconv_k(const float* __restrict__ x, unsigned short* __restrict__ xb, int n4){
    int i = blockIdx.x*256 + threadIdx.x;
    if (i < n4){
        const float4* p = (const float4*)x + i;
        float4 v = *p;
        unsigned short o0 = f2bf(v.x), o1 = f2bf(v.y), o2 = f2bf(v.z), o3 = f2bf(v.w);
        unsigned pack0 = (unsigned)o0 | ((unsigned)o1 << 16);
        unsigned pack1 = (unsigned)o2 | ((unsigned)o3 << 16);
        ((unsigned*)xb)[i*2]   = pack0;
        ((unsigned*)xb)[i*2+1] = pack1;
    }
}

// Ws[k][n],Wn[k][n] f32 -> combined transposed bf16 Wt[n][k]
__global__ void prepw_k(const float* __restrict__ Ws, const float* __restrict__ Wn,
                        unsigned short* __restrict__ Wt, int D, int Npad){
    int i = blockIdx.x*256 + threadIdx.x;   // i = n*128 + k
    int n = i >> 7, k = i & 127;
    if (n < Npad){
        float v = 0.f;
        if (n < D)           v = Ws[k*D + n];
        else if (n < 2*D)    v = Wn[k*D + (n - D)];
        Wt[n*128 + k] = f2bf(v);
    }
}

// ---------------- MFMA GEMM ----------------
// Block: 256 thr = 4 waves (2M x 2N of 64x64). Tile BM=128, BN=128 (cols of [Ws|Wn]).
// A staged in LDS via global_load_lds w/ XOR chunk swizzle; B fragments in registers.

__global__ __launch_bounds__(256) void gemm_mfma_k(
        const unsigned short* __restrict__ hb,   // [M][128] bf16
        const unsigned short* __restrict__ Wt,   // [Npad][128] bf16
        const float* __restrict__ bias,
        unsigned short* __restrict__ Y,          // [M][Dpad] bf16
        unsigned short* __restrict__ Z,          // [M][Dpad] bf16
        int M, int D, int Dpad){
    __shared__ char ldsA[128*256];               // 128 rows x 256B
    const int t = threadIdx.x;
    const int lane = t & 63;
    const int w = t >> 6;
    const int wm = w >> 1, wn = w & 1;
    const int tile = blockIdx.x * 128;
    const int cbase = blockIdx.y * 128;

    #pragma unroll
    for (int i = 0; i < 8; ++i){
        int chunkid = i*4 + w;
        int lin = chunkid*64 + lane;
        int row = lin >> 4;
        int cs  = lin & 15;
        int grow = tile + row; if (grow >= M) grow = M - 1;
        const char* src = (const char*)hb + (size_t)grow*256 + ((size_t)(cs ^ (row & 7)) << 4);
        __builtin_amdgcn_global_load_lds(
            (const __attribute__((address_space(1))) void*)src,
            (__attribute__((address_space(3))) void*)(ldsA + (size_t)chunkid*1024 + (size_t)lane*16),
            16, 0, 0);
    }

    short8 bfrag[4][4];
    {
        int ncol = cbase + wn*64;
        #pragma unroll
        for (int n = 0; n < 4; ++n){
            int wrow = ncol + n*16 + (lane & 15);
            const unsigned short* bp = Wt + (size_t)wrow*128 + ((lane >> 4) * 8);
            #pragma unroll
            for (int kk = 0; kk < 4; ++kk)
                bfrag[n][kk] = *(const short8*)(bp + kk*32);
        }
    }

    float4v acc[4][4];
    #pragma unroll
    for (int m = 0; m < 4; ++m)
        #pragma unroll
        for (int n = 0; n < 4; ++n)
            acc[m][n] = (float4v){0.f,0.f,0.f,0.f};

    __syncthreads();

    #pragma unroll
    for (int m = 0; m < 4; ++m){
        int r = wm*64 + m*16 + (lane & 15);
        #pragma unroll
        for (int kk = 0; kk < 4; ++kk){
            int c = kk*4 + (lane >> 4);
            short8 a = *(const short8*)(ldsA + (size_t)r*256 + ((size_t)(c ^ (r & 7)) << 4));
            #pragma unroll
            for (int n = 0; n < 4; ++n)
                acc[m][n] = __builtin_amdgcn_mfma_f32_16x16x32_bf16(a, bfrag[n][kk], acc[m][n], 0, 0, 0);
        }
    }

    #pragma unroll
    for (int m = 0; m < 4; ++m){
        #pragma unroll
        for (int n = 0; n < 4; ++n){
            int c = cbase + wn*64 + n*16 + (lane & 15);
            #pragma unroll
            for (int j = 0; j < 4; ++j){
                int r = tile + wm*64 + m*16 + (lane >> 4)*4 + j;
                if (r < M){
                    float v = acc[m][n][j];
                    if (c < D){
                        v += bias[c];
                        Y[(size_t)r*Dpad + c] = f2bf(v);
                    } else if (c < 2*D){
                        Z[(size_t)r*Dpad + (c - D)] = f2bf(v);
                    }
                }
            }
        }
    }
}

// ---------------- aggregation ----------------
// out = relu(Y + mean(Z[src])). One wave per node, lane covers feats {2l,2l+1}.
// 8 edges batched per iteration for memory-level parallelism.

__global__ __launch_bounds__(256) void agg128_k(
        const unsigned short* __restrict__ Yb, const unsigned short* __restrict__ Zb,
        const int* __restrict__ row_ptr, const int* __restrict__ ssorted,
        unsigned short* __restrict__ hout, int N){
    const int lane = threadIdx.x & 63;
    const int node = blockIdx.x*4 + (threadIdx.x >> 6);
    if (node >= N) return;
    const int beg = row_ptr[node], end = row_ptr[node+1];
    const float inv = 1.0f / fmaxf((float)(end - beg), 1.0f);
    float a0 = 0.f, a1 = 0.f;
    for (int e = beg; e < end; e += 8){
        int s[8];
        #pragma unroll
        for (int j = 0; j < 8; ++j){
            int ee = e + j; if (ee >= end) ee = end - 1;
            s[j] = ssorted[ee];
        }
        unsigned u[8];
        #pragma unroll
        for (int j = 0; j < 8; ++j)
            u[j] = *(const unsigned*)(Zb + (size_t)s[j]*128 + 2*lane);
        #pragma unroll
        for (int j = 0; j < 8; ++j){
            if (e + j < end){ a0 += bf_lo(u[j]); a1 += bf_hi(u[j]); }
        }
    }
    unsigned yu = *(const unsigned*)(Yb + (size_t)node*128 + 2*lane);
    float r0 = bf_lo(yu) + a0*inv;
    float r1 = bf_hi(yu) + a1*inv;
    r0 = fmaxf(r0, 0.f); r1 = fmaxf(r1, 0.f);
    unsigned o = (unsigned)f2bf(r0) | ((unsigned)f2bf(r1) << 16);
    *(unsigned*)(hout + (size_t)node*128 + 2*lane) = o;
}

// final layer: D=47 (Dpad=48), f32 out, no relu
__global__ __launch_bounds__(256) void aggfin_k(
        const unsigned short* __restrict__ Yb, const unsigned short* __restrict__ Zb,
        const int* __restrict__ row_ptr, const int* __restrict__ ssorted,
        float* __restrict__ out, int N){
    const int lane = threadIdx.x & 63;
    const int node = blockIdx.x*4 + (threadIdx.x >> 6);
    if (node >= N) return;
    const int beg = row_ptr[node], end = row_ptr[node+1];
    const float inv = 1.0f / fmaxf((float)(end - beg), 1.0f);
    float a0 = 0.f, a1 = 0.f;
    if (lane < 24){
        for (int e = beg; e < end; e += 8){
            int s[8];
            #pragma unroll
            for (int j = 0; j < 8; ++j){
                int ee = e + j; if (ee >= end) ee = end - 1;
                s[j] = ssorted[ee];
            }
            unsigned u[8];
            #pragma unroll
            for (int j = 0; j < 8; ++j)
                u[j] = *(const unsigned*)(Zb + (size_t)s[j]*48 + 2*lane);
            #pragma unroll
            for (int j = 0; j < 8; ++j){
                if (e + j < end){ a0 += bf_lo(u[j]); a1 += bf_hi(u[j]); }
            }
        }
        unsigned yu = *(const unsigned*)(Yb + (size_t)node*48 + 2*lane);
        int f0 = 2*lane, f1 = 2*lane + 1;
        float r0 = bf_lo(yu) + a0*inv;
        float r1 = bf_hi(yu) + a1*inv;
        out[(size_t)node*47 + f0] = r0;
        if (f1 < 47) out[(size_t)node*47 + f1] = r1;
    }
}

// ---------------- launch ----------------

extern "C" void kernel_launch(void* const* d_in, const int* in_sizes, int n_in,
                              void* d_out, int out_size, void* d_ws, size_t ws_size,
                              hipStream_t stream){
    const float* x   = (const float*)d_in[0];
    const int*   src = (const int*)  d_in[1];
    const int*   dstv= (const int*)  d_in[2];
    const float* Ws0 = (const float*)d_in[3];
    const float* Wn0 = (const float*)d_in[4];
    const float* b0  = (const float*)d_in[5];
    const float* Ws1 = (const float*)d_in[6];
    const float* Wn1 = (const float*)d_in[7];
    const float* b1  = (const float*)d_in[8];
    const float* Ws2 = (const float*)d_in[9];
    const float* Wn2 = (const float*)d_in[10];
    const float* b2  = (const float*)d_in[11];
    float* out = (float*)d_out;
    const int N = NN, E = NE;

    char* w = (char*)d_ws;
    size_t off = 0;
    auto alloc = [&](size_t bytes)->char*{
        char* p = w + off; off += (bytes + 255) & ~(size_t)255; return p;
    };
    int*   counts  = (int*)  alloc((size_t)N*4);
    int*   row_ptr = (int*)  alloc((size_t)(N+1)*4);
    int*   ssorted = (int*)  alloc((size_t)E*4);
    int*   bsum    = (int*)  alloc(4096);
    unsigned short* xb  = (unsigned short*)alloc((size_t)N*F*2);
    unsigned short* hA  = (unsigned short*)alloc((size_t)N*F*2);
    unsigned short* hB  = (unsigned short*)alloc((size_t)N*F*2);
    unsigned short* Yb  = (unsigned short*)alloc((size_t)N*F*2);
    unsigned short* Zb  = (unsigned short*)alloc((size_t)N*F*2);
    unsigned short* Wt0 = (unsigned short*)alloc((size_t)256*128*2);
    unsigned short* Wt1 = (unsigned short*)alloc((size_t)256*128*2);
    unsigned short* Wt2 = (unsigned short*)alloc((size_t)128*128*2);
    (void)ws_size; (void)n_in; (void)in_sizes; (void)out_size;

    const int NB = (N + CHUNK - 1)/CHUNK;

    hipMemsetAsync(counts, 0, (size_t)N*4, stream);
    hist_k      <<<(E+255)/256, 256, 0, stream>>>(dstv, counts, E);
    chunk_sum_k <<<NB, 256, 0, stream>>>(counts, bsum, N);
    scan_small_k<<<1, 64, 0, stream>>>(bsum, NB);
    chunk_scan_k<<<NB, 256, 0, stream>>>(counts, bsum, row_ptr, N, E);
    hipMemsetAsync(counts, 0, (size_t)N*4, stream);
    scatter_k   <<<(E+255)/256, 256, 0, stream>>>(src, dstv, row_ptr, counts, ssorted, E);

    xconv_k<<<(N*F/4 + 255)/256, 256, 0, stream>>>(x, xb, N*F/4);
    prepw_k<<<(256*128 + 255)/256, 256, 0, stream>>>(Ws0, Wn0, Wt0, 128, 256);
    prepw_k<<<(256*128 + 255)/256, 256, 0, stream>>>(Ws1, Wn1, Wt1, 128, 256);
    prepw_k<<<(128*128 + 255)/256, 256, 0, stream>>>(Ws2, Wn2, Wt2, 47, 128);

    const int GM = (N + 127)/128;
    const int GA = (N + 3)/4;

    gemm_mfma_k<<<dim3(GM,2), 256, 0, stream>>>(xb, Wt0, b0, Yb, Zb, N, 128, 128);
    agg128_k   <<<GA, 256, 0, stream>>>(Yb, Zb, row_ptr, ssorted, hA, N);
    gemm_mfma_k<<<dim3(GM,2), 256, 0, stream>>>(hA, Wt1, b1, Yb, Zb, N, 128, 128);
    agg128_k   <<<GA, 256, 0, stream>>>(Yb, Zb, row_ptr, ssorted, hB, N);
    gemm_mfma_k<<<dim3(GM,1), 256, 0, stream>>>(hB, Wt2, b2, Yb, Zb, N, 47, 48);
    aggfin_k   <<<GA, 256, 0, stream>>>(Yb, Zb, row_ptr, ssorted, out, N);
}

// Round 4
// 553.477 us; speedup vs baseline: 2.0801x; 1.0238x over previous
//
#include <hip/hip_runtime.h>
#include <cstdint>
#include <cstddef>

static const int NN = 100000;
static const int NE = 1600000;
static const int F  = 128;       // K dim (feature width)
static const int CHUNK = 1024;   // scan chunk
static const int BKT_SHIFT = 10;
static const int NBKT = (NN + (1 << BKT_SHIFT) - 1) >> BKT_SHIFT;   // 98

typedef __attribute__((ext_vector_type(8))) short short8;
typedef __attribute__((ext_vector_type(4))) float float4v;

static __device__ __forceinline__ unsigned short f2bf(float f){
    unsigned u = __builtin_bit_cast(unsigned, f);
    unsigned r = (u + 0x7FFFu + ((u >> 16) & 1u)) >> 16;
    return (unsigned short)r;
}
static __device__ __forceinline__ float bf_lo(unsigned u){
    return __builtin_bit_cast(float, u << 16);
}
static __device__ __forceinline__ float bf_hi(unsigned u){
    return __builtin_bit_cast(float, u & 0xFFFF0000u);
}

// ---------------- CSR build ----------------

__global__ void hist_k(const int* __restrict__ dst, int* __restrict__ counts, int E){
    int e = blockIdx.x*256 + threadIdx.x;
    if (e < E) atomicAdd(&counts[dst[e]], 1);
}

__global__ void chunk_sum_k(const int* __restrict__ counts, int* __restrict__ bsum, int N){
    __shared__ int sm[256];
    int base = blockIdx.x*CHUNK;
    int t = threadIdx.x;
    int s = 0;
    #pragma unroll
    for (int j = 0; j < 4; ++j){
        int idx = base + j*256 + t;
        s += (idx < N) ? counts[idx] : 0;
    }
    sm[t] = s; __syncthreads();
    for (int off = 128; off > 0; off >>= 1){
        if (t < off) sm[t] += sm[t+off];
        __syncthreads();
    }
    if (t == 0) bsum[blockIdx.x] = sm[0];
}

__global__ void scan_small_k(int* __restrict__ bsum, int nb){
    if (blockIdx.x == 0 && threadIdx.x == 0){
        int run = 0;
        for (int i = 0; i < nb; ++i){ int v = bsum[i]; bsum[i] = run; run += v; }
    }
}

__global__ void chunk_scan_k(const int* __restrict__ counts, const int* __restrict__ bsum,
                             int* __restrict__ row_ptr, int N, int E){
    __shared__ int sm[256];
    int base = blockIdx.x*CHUNK;
    int t = threadIdx.x;
    int v[4]; int s = 0;
    #pragma unroll
    for (int j = 0; j < 4; ++j){
        int idx = base + t*4 + j;
        int c = (idx < N) ? counts[idx] : 0;
        v[j] = s; s += c;
    }
    sm[t] = s; __syncthreads();
    for (int off = 1; off < 256; off <<= 1){
        int add = (t >= off) ? sm[t-off] : 0;
        __syncthreads();
        sm[t] += add;
        __syncthreads();
    }
    int texcl = sm[t] - s;
    int co = bsum[blockIdx.x];
    #pragma unroll
    for (int j = 0; j < 4; ++j){
        int idx = base + t*4 + j;
        if (idx < N) row_ptr[idx] = co + texcl + v[j];
    }
    if (base == 0 && t == 0) row_ptr[N] = E;
}

// bucket-scatter (src,dst) pairs into per-bucket regions of the pair array.
// bucket b = dst>>BKT_SHIFT; region origin = row_ptr[b<<BKT_SHIFT].
__global__ __launch_bounds__(256) void bscatter_k(
        const int* __restrict__ src, const int* __restrict__ dst,
        const int* __restrict__ row_ptr, int* __restrict__ bfill,
        int2* __restrict__ pairs, int E){
    __shared__ int hist[NBKT];
    __shared__ int gbase[NBKT];
    const int t = threadIdx.x;
    for (int i = t; i < NBKT; i += 256) hist[i] = 0;
    __syncthreads();
    const int e0 = blockIdx.x * 2048;
    int s[8], d[8], b[8], r[8];
    #pragma unroll
    for (int j = 0; j < 8; ++j){
        int e = e0 + j*256 + t;
        if (e < E){
            s[j] = src[e]; d[j] = dst[e];
            b[j] = d[j] >> BKT_SHIFT;
            r[j] = atomicAdd(&hist[b[j]], 1);
        }
    }
    __syncthreads();
    for (int i = t; i < NBKT; i += 256){
        int h = hist[i];
        int base = 0;
        if (h) base = atomicAdd(&bfill[i], h);
        gbase[i] = row_ptr[i << BKT_SHIFT] + base;
    }
    __syncthreads();
    #pragma unroll
    for (int j = 0; j < 8; ++j){
        int e = e0 + j*256 + t;
        if (e < E)
            pairs[gbase[b[j]] + r[j]] = make_int2(s[j], d[j]);
    }
}

// final scatter: pairs (bucket-ordered) -> ssorted via per-node fill counters.
// writes land in the same narrow index window the block reads from.
__global__ __launch_bounds__(256) void fscatter_k(
        const int2* __restrict__ pairs, const int* __restrict__ row_ptr,
        int* __restrict__ fill, int* __restrict__ ssorted, int E){
    const int t = threadIdx.x;
    const int e0 = blockIdx.x * 2048;
    #pragma unroll
    for (int j = 0; j < 8; ++j){
        int e = e0 + j*256 + t;
        if (e < E){
            int2 p = pairs[e];
            int pos = row_ptr[p.y] + atomicAdd(&fill[p.y], 1);
            ssorted[pos] = p.x;
        }
    }
}

// ---------------- conversions ----------------

__global__ void xconv_k(const float* __restrict__ x, unsigned short* __restrict__ xb, int n4){
    int i = blockIdx.x*256 + threadIdx.x;
    if (i < n4){
        const float4* p = (const float4*)x + i;
        float4 v = *p;
        unsigned short o0 = f2bf(v.x), o1 = f2bf(v.y), o2 = f2bf(v.z), o3 = f2bf(v.w);
        unsigned pack0 = (unsigned)o0 | ((unsigned)o1 << 16);
        unsigned pack1 = (unsigned)o2 | ((unsigned)o3 << 16);
        ((unsigned*)xb)[i*2]   = pack0;
        ((unsigned*)xb)[i*2+1] = pack1;
    }
}

// Ws[k][n],Wn[k][n] f32 -> combined transposed bf16 Wt[n][k]
__global__ void prepw_k(const float* __restrict__ Ws, const float* __restrict__ Wn,
                        unsigned short* __restrict__ Wt, int D, int Npad){
    int i = blockIdx.x*256 + threadIdx.x;   // i = n*128 + k
    int n = i >> 7, k = i & 127;
    if (n < Npad){
        float v = 0.f;
        if (n < D)           v = Ws[k*D + n];
        else if (n < 2*D)    v = Wn[k*D + (n - D)];
        Wt[n*128 + k] = f2bf(v);
    }
}

// ---------------- MFMA GEMM ----------------
// Block: 256 thr = 4 waves (2M x 2N of 64x64). Tile BM=128, BN=128 (cols of [Ws|Wn]).
// A staged in LDS via global_load_lds w/ XOR chunk swizzle; B fragments in registers.

__global__ __launch_bounds__(256) void gemm_mfma_k(
        const unsigned short* __restrict__ hb,   // [M][128] bf16
        const unsigned short* __restrict__ Wt,   // [Npad][128] bf16
        const float* __restrict__ bias,
        unsigned short* __restrict__ Y,          // [M][Dpad] bf16
        unsigned short* __restrict__ Z,          // [M][Dpad] bf16
        int M, int D, int Dpad){
    __shared__ char ldsA[128*256];               // 128 rows x 256B
    const int t = threadIdx.x;
    const int lane = t & 63;
    const int w = t >> 6;
    const int wm = w >> 1, wn = w & 1;
    const int tile = blockIdx.x * 128;
    const int cbase = blockIdx.y * 128;

    #pragma unroll
    for (int i = 0; i < 8; ++i){
        int chunkid = i*4 + w;
        int lin = chunkid*64 + lane;
        int row = lin >> 4;
        int cs  = lin & 15;
        int grow = tile + row; if (grow >= M) grow = M - 1;
        const char* src = (const char*)hb + (size_t)grow*256 + ((size_t)(cs ^ (row & 7)) << 4);
        __builtin_amdgcn_global_load_lds(
            (const __attribute__((address_space(1))) void*)src,
            (__attribute__((address_space(3))) void*)(ldsA + (size_t)chunkid*1024 + (size_t)lane*16),
            16, 0, 0);
    }

    short8 bfrag[4][4];
    {
        int ncol = cbase + wn*64;
        #pragma unroll
        for (int n = 0; n < 4; ++n){
            int wrow = ncol + n*16 + (lane & 15);
            const unsigned short* bp = Wt + (size_t)wrow*128 + ((lane >> 4) * 8);
            #pragma unroll
            for (int kk = 0; kk < 4; ++kk)
                bfrag[n][kk] = *(const short8*)(bp + kk*32);
        }
    }

    float4v acc[4][4];
    #pragma unroll
    for (int m = 0; m < 4; ++m)
        #pragma unroll
        for (int n = 0; n < 4; ++n)
            acc[m][n] = (float4v){0.f,0.f,0.f,0.f};

    __syncthreads();

    #pragma unroll
    for (int m = 0; m < 4; ++m){
        int r = wm*64 + m*16 + (lane & 15);
        #pragma unroll
        for (int kk = 0; kk < 4; ++kk){
            int c = kk*4 + (lane >> 4);
            short8 a = *(const short8*)(ldsA + (size_t)r*256 + ((size_t)(c ^ (r & 7)) << 4));
            #pragma unroll
            for (int n = 0; n < 4; ++n)
                acc[m][n] = __builtin_amdgcn_mfma_f32_16x16x32_bf16(a, bfrag[n][kk], acc[m][n], 0, 0, 0);
        }
    }

    #pragma unroll
    for (int m = 0; m < 4; ++m){
        #pragma unroll
        for (int n = 0; n < 4; ++n){
            int c = cbase + wn*64 + n*16 + (lane & 15);
            #pragma unroll
            for (int j = 0; j < 4; ++j){
                int r = tile + wm*64 + m*16 + (lane >> 4)*4 + j;
                if (r < M){
                    float v = acc[m][n][j];
                    if (c < D){
                        v += bias[c];
                        Y[(size_t)r*Dpad + c] = f2bf(v);
                    } else if (c < 2*D){
                        Z[(size_t)r*Dpad + (c - D)] = f2bf(v);
                    }
                }
            }
        }
    }
}

// ---------------- aggregation ----------------
// out = relu(Y + mean(Z[src])). One wave per node, lane covers feats {2l,2l+1}.
// 8 edges batched per iteration for memory-level parallelism.

__global__ __launch_bounds__(256) void agg128_k(
        const unsigned short* __restrict__ Yb, const unsigned short* __restrict__ Zb,
        const int* __restrict__ row_ptr, const int* __restrict__ ssorted,
        unsigned short* __restrict__ hout, int N){
    const int lane = threadIdx.x & 63;
    const int node = blockIdx.x*4 + (threadIdx.x >> 6);
    if (node >= N) return;
    const int beg = row_ptr[node], end = row_ptr[node+1];
    const float inv = 1.0f / fmaxf((float)(end - beg), 1.0f);
    float a0 = 0.f, a1 = 0.f;
    for (int e = beg; e < end; e += 8){
        int s[8];
        #pragma unroll
        for (int j = 0; j < 8; ++j){
            int ee = e + j; if (ee >= end) ee = end - 1;
            s[j] = ssorted[ee];
        }
        unsigned u[8];
        #pragma unroll
        for (int j = 0; j < 8; ++j)
            u[j] = *(const unsigned*)(Zb + (size_t)s[j]*128 + 2*lane);
        #pragma unroll
        for (int j = 0; j < 8; ++j){
            if (e + j < end){ a0 += bf_lo(u[j]); a1 += bf_hi(u[j]); }
        }
    }
    unsigned yu = *(const unsigned*)(Yb + (size_t)node*128 + 2*lane);
    float r0 = bf_lo(yu) + a0*inv;
    float r1 = bf_hi(yu) + a1*inv;
    r0 = fmaxf(r0, 0.f); r1 = fmaxf(r1, 0.f);
    unsigned o = (unsigned)f2bf(r0) | ((unsigned)f2bf(r1) << 16);
    *(unsigned*)(hout + (size_t)node*128 + 2*lane) = o;
}

// final layer: D=47 (Dpad=48), f32 out, no relu
__global__ __launch_bounds__(256) void aggfin_k(
        const unsigned short* __restrict__ Yb, const unsigned short* __restrict__ Zb,
        const int* __restrict__ row_ptr, const int* __restrict__ ssorted,
        float* __restrict__ out, int N){
    const int lane = threadIdx.x & 63;
    const int node = blockIdx.x*4 + (threadIdx.x >> 6);
    if (node >= N) return;
    const int beg = row_ptr[node], end = row_ptr[node+1];
    const float inv = 1.0f / fmaxf((float)(end - beg), 1.0f);
    float a0 = 0.f, a1 = 0.f;
    if (lane < 24){
        for (int e = beg; e < end; e += 8){
            int s[8];
            #pragma unroll
            for (int j = 0; j < 8; ++j){
                int ee = e + j; if (ee >= end) ee = end - 1;
                s[j] = ssorted[ee];
            }
            unsigned u[8];
            #pragma unroll
            for (int j = 0; j < 8; ++j)
                u[j] = *(const unsigned*)(Zb + (size_t)s[j]*48 + 2*lane);
            #pragma unroll
            for (int j = 0; j < 8; ++j){
                if (e + j < end){ a0 += bf_lo(u[j]); a1 += bf_hi(u[j]); }
            }
        }
        unsigned yu = *(const unsigned*)(Yb + (size_t)node*48 + 2*lane);
        int f0 = 2*lane, f1 = 2*lane + 1;
        float r0 = bf_lo(yu) + a0*inv;
        float r1 = bf_hi(yu) + a1*inv;
        out[(size_t)node*47 + f0] = r0;
        if (f1 < 47) out[(size_t)node*47 + f1] = r1;
    }
}

// ---------------- launch ----------------

extern "C" void kernel_launch(void* const* d_in, const int* in_sizes, int n_in,
                              void* d_out, int out_size, void* d_ws, size_t ws_size,
                              hipStream_t stream){
    const float* x   = (const float*)d_in[0];
    const int*   src = (const int*)  d_in[1];
    const int*   dstv= (const int*)  d_in[2];
    const float* Ws0 = (const float*)d_in[3];
    const float* Wn0 = (const float*)d_in[4];
    const float* b0  = (const float*)d_in[5];
    const float* Ws1 = (const float*)d_in[6];
    const float* Wn1 = (const float*)d_in[7];
    const float* b1  = (const float*)d_in[8];
    const float* Ws2 = (const float*)d_in[9];
    const float* Wn2 = (const float*)d_in[10];
    const float* b2  = (const float*)d_in[11];
    float* out = (float*)d_out;
    const int N = NN, E = NE;

    char* w = (char*)d_ws;
    size_t off = 0;
    auto alloc = [&](size_t bytes)->char*{
        char* p = w + off; off += (bytes + 255) & ~(size_t)255; return p;
    };
    int*   counts  = (int*)  alloc((size_t)N*4);
    int*   row_ptr = (int*)  alloc((size_t)(N+1)*4);
    int*   ssorted = (int*)  alloc((size_t)E*4);
    int*   bsum    = (int*)  alloc(4096);
    int*   bfill   = (int*)  alloc((size_t)NBKT*4);
    int2*  pairs   = (int2*) alloc((size_t)E*8);
    unsigned short* xb  = (unsigned short*)alloc((size_t)N*F*2);
    unsigned short* hA  = (unsigned short*)alloc((size_t)N*F*2);
    unsigned short* hB  = (unsigned short*)alloc((size_t)N*F*2);
    unsigned short* Yb  = (unsigned short*)alloc((size_t)N*F*2);
    unsigned short* Zb  = (unsigned short*)alloc((size_t)N*F*2);
    unsigned short* Wt0 = (unsigned short*)alloc((size_t)256*128*2);
    unsigned short* Wt1 = (unsigned short*)alloc((size_t)256*128*2);
    unsigned short* Wt2 = (unsigned short*)alloc((size_t)128*128*2);
    (void)ws_size; (void)n_in; (void)in_sizes; (void)out_size;

    const int NB = (N + CHUNK - 1)/CHUNK;
    const int GE = (E + 2047)/2048;

    hipMemsetAsync(counts, 0, (size_t)N*4, stream);
    hipMemsetAsync(bfill, 0, (size_t)NBKT*4, stream);
    hist_k      <<<(E+255)/256, 256, 0, stream>>>(dstv, counts, E);
    chunk_sum_k <<<NB, 256, 0, stream>>>(counts, bsum, N);
    scan_small_k<<<1, 64, 0, stream>>>(bsum, NB);
    chunk_scan_k<<<NB, 256, 0, stream>>>(counts, bsum, row_ptr, N, E);
    bscatter_k  <<<GE, 256, 0, stream>>>(src, dstv, row_ptr, bfill, pairs, E);
    hipMemsetAsync(counts, 0, (size_t)N*4, stream);
    fscatter_k  <<<GE, 256, 0, stream>>>(pairs, row_ptr, counts, ssorted, E);

    xconv_k<<<(N*F/4 + 255)/256, 256, 0, stream>>>(x, xb, N*F/4);
    prepw_k<<<(256*128 + 255)/256, 256, 0, stream>>>(Ws0, Wn0, Wt0, 128, 256);
    prepw_k<<<(256*128 + 255)/256, 256, 0, stream>>>(Ws1, Wn1, Wt1, 128, 256);
    prepw_k<<<(128*128 + 255)/256, 256, 0, stream>>>(Ws2, Wn2, Wt2, 47, 128);

    const int GM = (N + 127)/128;
    const int GA = (N + 3)/4;

    gemm_mfma_k<<<dim3(GM,2), 256, 0, stream>>>(xb, Wt0, b0, Yb, Zb, N, 128, 128);
    agg128_k   <<<GA, 256, 0, stream>>>(Yb, Zb, row_ptr, ssorted, hA, N);
    gemm_mfma_k<<<dim3(GM,2), 256, 0, stream>>>(hA, Wt1, b1, Yb, Zb, N, 128, 128);
    agg128_k   <<<GA, 256, 0, stream>>>(Yb, Zb, row_ptr, ssorted, hB, N);
    gemm_mfma_k<<<dim3(GM,1), 256, 0, stream>>>(hB, Wt2, b2, Yb, Zb, N, 47, 48);
    aggfin_k   <<<GA, 256, 0, stream>>>(Yb, Zb, row_ptr, ssorted, out, N);
}

// Round 5
// 527.189 us; speedup vs baseline: 2.1838x; 1.0499x over previous
//
#include <hip/hip_runtime.h>
#include <cstdint>
#include <cstddef>

static const int NN = 100000;
static const int NE = 1600000;
static const int F  = 128;       // K dim (feature width)
static const int CHUNK = 1024;   // scan chunk
static const int BKT_SHIFT = 10;
static const int NBKT = (NN + (1 << BKT_SHIFT) - 1) >> BKT_SHIFT;   // 98 (must be <= 256)

typedef __attribute__((ext_vector_type(8))) short short8;
typedef __attribute__((ext_vector_type(4))) float float4v;
typedef __attribute__((ext_vector_type(2))) float f32x2;

static __device__ __forceinline__ unsigned short f2bf(float f){
    unsigned u = __builtin_bit_cast(unsigned, f);
    unsigned r = (u + 0x7FFFu + ((u >> 16) & 1u)) >> 16;
    return (unsigned short)r;
}
static __device__ __forceinline__ float bf_lo(unsigned u){
    return __builtin_bit_cast(float, u << 16);
}
static __device__ __forceinline__ float bf_hi(unsigned u){
    return __builtin_bit_cast(float, u & 0xFFFF0000u);
}

// ---------------- CSR build ----------------

__global__ void hist_k(const int* __restrict__ dst, int* __restrict__ counts, int E){
    int e = blockIdx.x*256 + threadIdx.x;
    if (e < E) atomicAdd(&counts[dst[e]], 1);
}

__global__ void chunk_sum_k(const int* __restrict__ counts, int* __restrict__ bsum, int N){
    __shared__ int sm[256];
    int base = blockIdx.x*CHUNK;
    int t = threadIdx.x;
    int s = 0;
    #pragma unroll
    for (int j = 0; j < 4; ++j){
        int idx = base + j*256 + t;
        s += (idx < N) ? counts[idx] : 0;
    }
    sm[t] = s; __syncthreads();
    for (int off = 128; off > 0; off >>= 1){
        if (t < off) sm[t] += sm[t+off];
        __syncthreads();
    }
    if (t == 0) bsum[blockIdx.x] = sm[0];
}

// fused: per-block offset from bsum (NB<=256), chunk-local scan, row_ptr write,
// and zeroing of counts (reused as fill[] by fscatter_k).
__global__ void chunk_scan_k(int* __restrict__ counts, const int* __restrict__ bsum,
                             int* __restrict__ row_ptr, int N, int E){
    __shared__ int sm[256];
    __shared__ int co_sh;
    int t = threadIdx.x;
    int p = (t < (int)blockIdx.x) ? bsum[t] : 0;
    sm[t] = p; __syncthreads();
    for (int off = 128; off > 0; off >>= 1){
        if (t < off) sm[t] += sm[t+off];
        __syncthreads();
    }
    if (t == 0) co_sh = sm[0];
    __syncthreads();
    int co = co_sh;
    __syncthreads();                    // done with sm before reuse

    int base = blockIdx.x*CHUNK;
    int v[4]; int s = 0;
    #pragma unroll
    for (int j = 0; j < 4; ++j){
        int idx = base + t*4 + j;
        int c = (idx < N) ? counts[idx] : 0;
        v[j] = s; s += c;
    }
    sm[t] = s; __syncthreads();
    for (int off = 1; off < 256; off <<= 1){
        int add = (t >= off) ? sm[t-off] : 0;
        __syncthreads();
        sm[t] += add;
        __syncthreads();
    }
    int texcl = sm[t] - s;
    #pragma unroll
    for (int j = 0; j < 4; ++j){
        int idx = base + t*4 + j;
        if (idx < N){
            row_ptr[idx] = co + texcl + v[j];
            counts[idx] = 0;            // ready for fscatter fill
        }
    }
    if (base == 0 && t == 0) row_ptr[N] = E;
}

// bucket-scatter (src,dst) pairs into per-bucket regions of the pair array.
__global__ __launch_bounds__(256) void bscatter_k(
        const int* __restrict__ src, const int* __restrict__ dst,
        const int* __restrict__ row_ptr, int* __restrict__ bfill,
        int2* __restrict__ pairs, int E){
    __shared__ int hist[NBKT];
    __shared__ int gbase[NBKT];
    const int t = threadIdx.x;
    for (int i = t; i < NBKT; i += 256) hist[i] = 0;
    __syncthreads();
    const int e0 = blockIdx.x * 2048;
    int s[8], d[8], b[8], r[8];
    #pragma unroll
    for (int j = 0; j < 8; ++j){
        int e = e0 + j*256 + t;
        if (e < E){
            s[j] = src[e]; d[j] = dst[e];
            b[j] = d[j] >> BKT_SHIFT;
            r[j] = atomicAdd(&hist[b[j]], 1);
        }
    }
    __syncthreads();
    for (int i = t; i < NBKT; i += 256){
        int h = hist[i];
        int base = 0;
        if (h) base = atomicAdd(&bfill[i], h);
        gbase[i] = row_ptr[i << BKT_SHIFT] + base;
    }
    __syncthreads();
    #pragma unroll
    for (int j = 0; j < 8; ++j){
        int e = e0 + j*256 + t;
        if (e < E)
            pairs[gbase[b[j]] + r[j]] = make_int2(s[j], d[j]);
    }
}

// final scatter: bucket-ordered pairs -> ssorted; writes stay in a narrow window.
__global__ __launch_bounds__(256) void fscatter_k(
        const int2* __restrict__ pairs, const int* __restrict__ row_ptr,
        int* __restrict__ fill, int* __restrict__ ssorted, int E){
    const int t = threadIdx.x;
    const int e0 = blockIdx.x * 2048;
    #pragma unroll
    for (int j = 0; j < 8; ++j){
        int e = e0 + j*256 + t;
        if (e < E){
            int2 p = pairs[e];
            int pos = row_ptr[p.y] + atomicAdd(&fill[p.y], 1);
            ssorted[pos] = p.x;
        }
    }
}

// ---------------- conversions ----------------

__global__ void xconv_k(const float* __restrict__ x, unsigned short* __restrict__ xb, int n4){
    int i = blockIdx.x*256 + threadIdx.x;
    if (i < n4){
        const float4* p = (const float4*)x + i;
        float4 v = *p;
        unsigned short o0 = f2bf(v.x), o1 = f2bf(v.y), o2 = f2bf(v.z), o3 = f2bf(v.w);
        ((unsigned*)xb)[i*2]   = (unsigned)o0 | ((unsigned)o1 << 16);
        ((unsigned*)xb)[i*2+1] = (unsigned)o2 | ((unsigned)o3 << 16);
    }
}

// all three layers' weights -> combined transposed bf16 Wt[n][k] in one launch.
// ranges: [0,32768) Wt0 D=128 ; [32768,65536) Wt1 D=128 ; [65536,81920) Wt2 D=47.
__global__ void prepw_all_k(const float* __restrict__ Ws0, const float* __restrict__ Wn0,
                            const float* __restrict__ Ws1, const float* __restrict__ Wn1,
                            const float* __restrict__ Ws2, const float* __restrict__ Wn2,
                            unsigned short* __restrict__ Wt0, unsigned short* __restrict__ Wt1,
                            unsigned short* __restrict__ Wt2){
    int i = blockIdx.x*256 + threadIdx.x;
    const float* Ws; const float* Wn; unsigned short* Wt; int D; int idx;
    if (i < 32768){       Ws=Ws0; Wn=Wn0; Wt=Wt0; D=128; idx=i; }
    else if (i < 65536){  Ws=Ws1; Wn=Wn1; Wt=Wt1; D=128; idx=i-32768; }
    else {                Ws=Ws2; Wn=Wn2; Wt=Wt2; D=47;  idx=i-65536; }
    int n = idx >> 7, k = idx & 127;
    float v = 0.f;
    if (n < D)        v = Ws[k*D + n];
    else if (n < 2*D) v = Wn[k*D + (n - D)];
    Wt[n*128 + k] = f2bf(v);
}

// ---------------- MFMA GEMM ----------------
// Block: 256 thr = 4 waves (2M x 2N of 64x64). Tile BM=128, BN=128 (cols of [Ws|Wn]).
// A staged in LDS via global_load_lds w/ XOR chunk swizzle; B fragments in registers.

__global__ __launch_bounds__(256) void gemm_mfma_k(
        const unsigned short* __restrict__ hb,   // [M][128] bf16
        const unsigned short* __restrict__ Wt,   // [Npad][128] bf16
        const float* __restrict__ bias,
        unsigned short* __restrict__ Y,          // [M][Dpad] bf16
        unsigned short* __restrict__ Z,          // [M][Dpad] bf16
        int M, int D, int Dpad){
    __shared__ char ldsA[128*256];               // 128 rows x 256B
    const int t = threadIdx.x;
    const int lane = t & 63;
    const int w = t >> 6;
    const int wm = w >> 1, wn = w & 1;
    const int tile = blockIdx.x * 128;
    const int cbase = blockIdx.y * 128;

    #pragma unroll
    for (int i = 0; i < 8; ++i){
        int chunkid = i*4 + w;
        int lin = chunkid*64 + lane;
        int row = lin >> 4;
        int cs  = lin & 15;
        int grow = tile + row; if (grow >= M) grow = M - 1;
        const char* src = (const char*)hb + (size_t)grow*256 + ((size_t)(cs ^ (row & 7)) << 4);
        __builtin_amdgcn_global_load_lds(
            (const __attribute__((address_space(1))) void*)src,
            (__attribute__((address_space(3))) void*)(ldsA + (size_t)chunkid*1024 + (size_t)lane*16),
            16, 0, 0);
    }

    short8 bfrag[4][4];
    {
        int ncol = cbase + wn*64;
        #pragma unroll
        for (int n = 0; n < 4; ++n){
            int wrow = ncol + n*16 + (lane & 15);
            const unsigned short* bp = Wt + (size_t)wrow*128 + ((lane >> 4) * 8);
            #pragma unroll
            for (int kk = 0; kk < 4; ++kk)
                bfrag[n][kk] = *(const short8*)(bp + kk*32);
        }
    }

    float4v acc[4][4];
    #pragma unroll
    for (int m = 0; m < 4; ++m)
        #pragma unroll
        for (int n = 0; n < 4; ++n)
            acc[m][n] = (float4v){0.f,0.f,0.f,0.f};

    __syncthreads();

    #pragma unroll
    for (int m = 0; m < 4; ++m){
        int r = wm*64 + m*16 + (lane & 15);
        #pragma unroll
        for (int kk = 0; kk < 4; ++kk){
            int c = kk*4 + (lane >> 4);
            short8 a = *(const short8*)(ldsA + (size_t)r*256 + ((size_t)(c ^ (r & 7)) << 4));
            #pragma unroll
            for (int n = 0; n < 4; ++n)
                acc[m][n] = __builtin_amdgcn_mfma_f32_16x16x32_bf16(a, bfrag[n][kk], acc[m][n], 0, 0, 0);
        }
    }

    #pragma unroll
    for (int m = 0; m < 4; ++m){
        #pragma unroll
        for (int n = 0; n < 4; ++n){
            int c = cbase + wn*64 + n*16 + (lane & 15);
            #pragma unroll
            for (int j = 0; j < 4; ++j){
                int r = tile + wm*64 + m*16 + (lane >> 4)*4 + j;
                if (r < M){
                    float v = acc[m][n][j];
                    if (c < D){
                        v += bias[c];
                        Y[(size_t)r*Dpad + c] = f2bf(v);
                    } else if (c < 2*D){
                        Z[(size_t)r*Dpad + (c - D)] = f2bf(v);
                    }
                }
            }
        }
    }
}

// ---------------- aggregation ----------------
// out = relu(Y + mean(Z[src])). One wave per node; lanes 0-31 edge e, lanes 32-63
// edge e+1; each lane covers 4 feats via dwordx2. 16-edge batches for MLP.

__global__ __launch_bounds__(256) void agg128_k(
        const unsigned short* __restrict__ Yb, const unsigned short* __restrict__ Zb,
        const int* __restrict__ row_ptr, const int* __restrict__ ssorted,
        unsigned short* __restrict__ hout, int N){
    const int lane = threadIdx.x & 63;
    const int half = lane >> 5;
    const int sub  = lane & 31;
    const int node = blockIdx.x*4 + (threadIdx.x >> 6);
    if (node >= N) return;
    const int beg = __builtin_amdgcn_readfirstlane(row_ptr[node]);
    const int end = __builtin_amdgcn_readfirstlane(row_ptr[node+1]);
    const float inv = 1.0f / fmaxf((float)(end - beg), 1.0f);
    const char* zc = (const char*)Zb;
    const unsigned boff = (unsigned)(sub*8);
    f32x2 acc0 = {0.f,0.f}, acc1 = {0.f,0.f};
    int e = beg;
    for (; e + 16 <= end; e += 16){
        int s[8];
        #pragma unroll
        for (int j = 0; j < 8; ++j) s[j] = ssorted[e + 2*j + half];
        uint2 u[8];
        #pragma unroll
        for (int j = 0; j < 8; ++j)
            u[j] = *(const uint2*)(zc + ((unsigned)s[j]*256u + boff));
        #pragma unroll
        for (int j = 0; j < 8; ++j){
            f32x2 A = { bf_lo(u[j].x), bf_lo(u[j].y) };
            f32x2 B = { bf_hi(u[j].x), bf_hi(u[j].y) };
            acc0 += A; acc1 += B;
        }
    }
    if (e < end){
        #pragma unroll
        for (int j = 0; j < 8; ++j){
            int ei = e + 2*j + half;
            int ec = ei < end ? ei : end - 1;
            int sv = ssorted[ec];
            uint2 u = *(const uint2*)(zc + ((unsigned)sv*256u + boff));
            if (ei < end){
                f32x2 A = { bf_lo(u.x), bf_lo(u.y) };
                f32x2 B = { bf_hi(u.x), bf_hi(u.y) };
                acc0 += A; acc1 += B;
            }
        }
    }
    // combine the two edge-halves (lane l and l^32 hold the same feats)
    acc0.x += __shfl_xor(acc0.x, 32, 64);
    acc0.y += __shfl_xor(acc0.y, 32, 64);
    acc1.x += __shfl_xor(acc1.x, 32, 64);
    acc1.y += __shfl_xor(acc1.y, 32, 64);
    if (half == 0){
        uint2 yu = *(const uint2*)((const char*)Yb + (size_t)node*256 + sub*8);
        float r0 = bf_lo(yu.x) + acc0.x*inv;
        float r1 = bf_hi(yu.x) + acc1.x*inv;
        float r2 = bf_lo(yu.y) + acc0.y*inv;
        float r3 = bf_hi(yu.y) + acc1.y*inv;
        r0=fmaxf(r0,0.f); r1=fmaxf(r1,0.f); r2=fmaxf(r2,0.f); r3=fmaxf(r3,0.f);
        uint2 o;
        o.x = (unsigned)f2bf(r0) | ((unsigned)f2bf(r1) << 16);
        o.y = (unsigned)f2bf(r2) | ((unsigned)f2bf(r3) << 16);
        *(uint2*)((char*)hout + (size_t)node*256 + sub*8) = o;
    }
}

// final layer: D=47 (Dpad=48), f32 out, no relu. One wave per node; 4 edge-quarters
// of 16 lanes, 12 active lanes x 4 feats each.
__global__ __launch_bounds__(256) void aggfin_k(
        const unsigned short* __restrict__ Yb, const unsigned short* __restrict__ Zb,
        const int* __restrict__ row_ptr, const int* __restrict__ ssorted,
        float* __restrict__ out, int N){
    const int lane = threadIdx.x & 63;
    const int q   = lane >> 4;          // edge slot 0..3
    const int sub = lane & 15;          // feat group, active if <12
    const int node = blockIdx.x*4 + (threadIdx.x >> 6);
    if (node >= N) return;
    const int beg = __builtin_amdgcn_readfirstlane(row_ptr[node]);
    const int end = __builtin_amdgcn_readfirstlane(row_ptr[node+1]);
    const float inv = 1.0f / fmaxf((float)(end - beg), 1.0f);
    const char* zc = (const char*)Zb;
    const bool act = (sub < 12);
    const unsigned boff = (unsigned)(sub*8);
    f32x2 acc0 = {0.f,0.f}, acc1 = {0.f,0.f};
    int e = beg;
    for (; e + 16 <= end; e += 16){
        #pragma unroll
        for (int j = 0; j < 4; ++j){
            int sv = ssorted[e + 4*j + q];
            if (act){
                uint2 u = *(const uint2*)(zc + ((unsigned)sv*96u + boff));
                f32x2 A = { bf_lo(u.x), bf_lo(u.y) };
                f32x2 B = { bf_hi(u.x), bf_hi(u.y) };
                acc0 += A; acc1 += B;
            }
        }
    }
    if (e < end){
        #pragma unroll
        for (int j = 0; j < 4; ++j){
            int ei = e + 4*j + q;
            int ec = ei < end ? ei : end - 1;
            int sv = ssorted[ec];
            if (act && ei < end){
                uint2 u = *(const uint2*)(zc + ((unsigned)sv*96u + boff));
                f32x2 A = { bf_lo(u.x), bf_lo(u.y) };
                f32x2 B = { bf_hi(u.x), bf_hi(u.y) };
                acc0 += A; acc1 += B;
            }
        }
    }
    // reduce across the 4 quarters (lanes differing in bits 4,5)
    acc0.x += __shfl_xor(acc0.x, 16, 64); acc0.x += __shfl_xor(acc0.x, 32, 64);
    acc0.y += __shfl_xor(acc0.y, 16, 64); acc0.y += __shfl_xor(acc0.y, 32, 64);
    acc1.x += __shfl_xor(acc1.x, 16, 64); acc1.x += __shfl_xor(acc1.x, 32, 64);
    acc1.y += __shfl_xor(acc1.y, 16, 64); acc1.y += __shfl_xor(acc1.y, 32, 64);
    if (q == 0 && act){
        uint2 yu = *(const uint2*)((const char*)Yb + (size_t)node*96 + sub*8);
        float r0 = bf_lo(yu.x) + acc0.x*inv;
        float r1 = bf_hi(yu.x) + acc1.x*inv;
        float r2 = bf_lo(yu.y) + acc0.y*inv;
        float r3 = bf_hi(yu.y) + acc1.y*inv;
        int f = 4*sub;
        size_t o = (size_t)node*47 + f;
        out[o]   = r0;
        out[o+1] = r1;
        out[o+2] = r2;
        if (f + 3 < 47) out[o+3] = r3;
    }
}

// ---------------- launch ----------------

extern "C" void kernel_launch(void* const* d_in, const int* in_sizes, int n_in,
                              void* d_out, int out_size, void* d_ws, size_t ws_size,
                              hipStream_t stream){
    const float* x   = (const float*)d_in[0];
    const int*   src = (const int*)  d_in[1];
    const int*   dstv= (const int*)  d_in[2];
    const float* Ws0 = (const float*)d_in[3];
    const float* Wn0 = (const float*)d_in[4];
    const float* b0  = (const float*)d_in[5];
    const float* Ws1 = (const float*)d_in[6];
    const float* Wn1 = (const float*)d_in[7];
    const float* b1  = (const float*)d_in[8];
    const float* Ws2 = (const float*)d_in[9];
    const float* Wn2 = (const float*)d_in[10];
    const float* b2  = (const float*)d_in[11];
    float* out = (float*)d_out;
    const int N = NN, E = NE;

    char* w = (char*)d_ws;
    size_t off = 0;
    auto alloc = [&](size_t bytes)->char*{
        char* p = w + off; off += (bytes + 255) & ~(size_t)255; return p;
    };
    int*   cbuf    = (int*)  alloc((size_t)(N + NBKT)*4);   // counts | bfill, one memset
    int*   counts  = cbuf;
    int*   bfill   = cbuf + N;
    int*   row_ptr = (int*)  alloc((size_t)(N+1)*4);
    int*   ssorted = (int*)  alloc((size_t)E*4);
    int*   bsum    = (int*)  alloc(4096);
    int2*  pairs   = (int2*) alloc((size_t)E*8);
    unsigned short* xb  = (unsigned short*)alloc((size_t)N*F*2);
    unsigned short* hA  = (unsigned short*)alloc((size_t)N*F*2);
    unsigned short* hB  = (unsigned short*)alloc((size_t)N*F*2);
    unsigned short* Yb  = (unsigned short*)alloc((size_t)N*F*2);
    unsigned short* Zb  = (unsigned short*)alloc((size_t)N*F*2);
    unsigned short* Wt0 = (unsigned short*)alloc((size_t)256*128*2);
    unsigned short* Wt1 = (unsigned short*)alloc((size_t)256*128*2);
    unsigned short* Wt2 = (unsigned short*)alloc((size_t)128*128*2);
    (void)ws_size; (void)n_in; (void)in_sizes; (void)out_size;

    const int NB = (N + CHUNK - 1)/CHUNK;   // 98 <= 256 required by chunk_scan_k
    const int GE = (E + 2047)/2048;

    hipMemsetAsync(cbuf, 0, (size_t)(N + NBKT)*4, stream);
    hist_k      <<<(E+255)/256, 256, 0, stream>>>(dstv, counts, E);
    chunk_sum_k <<<NB, 256, 0, stream>>>(counts, bsum, N);
    chunk_scan_k<<<NB, 256, 0, stream>>>(counts, bsum, row_ptr, N, E);
    bscatter_k  <<<GE, 256, 0, stream>>>(src, dstv, row_ptr, bfill, pairs, E);
    fscatter_k  <<<GE, 256, 0, stream>>>(pairs, row_ptr, counts, ssorted, E);

    xconv_k<<<(N*F/4 + 255)/256, 256, 0, stream>>>(x, xb, N*F/4);
    prepw_all_k<<<320, 256, 0, stream>>>(Ws0, Wn0, Ws1, Wn1, Ws2, Wn2, Wt0, Wt1, Wt2);

    const int GM = (N + 127)/128;
    const int GA = (N + 3)/4;

    gemm_mfma_k<<<dim3(GM,2), 256, 0, stream>>>(xb, Wt0, b0, Yb, Zb, N, 128, 128);
    agg128_k   <<<GA, 256, 0, stream>>>(Yb, Zb, row_ptr, ssorted, hA, N);
    gemm_mfma_k<<<dim3(GM,2), 256, 0, stream>>>(hA, Wt1, b1, Yb, Zb, N, 128, 128);
    agg128_k   <<<GA, 256, 0, stream>>>(Yb, Zb, row_ptr, ssorted, hB, N);
    gemm_mfma_k<<<dim3(GM,1), 256, 0, stream>>>(hB, Wt2, b2, Yb, Zb, N, 47, 48);
    aggfin_k   <<<GA, 256, 0, stream>>>(Yb, Zb, row_ptr, ssorted, out, N);
}

// Round 6
// 485.762 us; speedup vs baseline: 2.3701x; 1.0853x over previous
//
#include <hip/hip_runtime.h>
#include <cstdint>
#include <cstddef>

static const int NN = 100000;
static const int NE = 1600000;
static const int F  = 128;       // K dim (feature width)
static const int CHUNK = 1024;   // scan chunk
static const int BKT_SHIFT = 10;
static const int NBKT = (NN + (1 << BKT_SHIFT) - 1) >> BKT_SHIFT;   // 98 (must be <= 256)

typedef __attribute__((ext_vector_type(8))) short short8;
typedef __attribute__((ext_vector_type(4))) float float4v;
typedef __attribute__((ext_vector_type(2))) float f32x2;

static __device__ __forceinline__ unsigned short f2bf(float f){
    unsigned u = __builtin_bit_cast(unsigned, f);
    unsigned r = (u + 0x7FFFu + ((u >> 16) & 1u)) >> 16;
    return (unsigned short)r;
}
static __device__ __forceinline__ float bf_lo(unsigned u){
    return __builtin_bit_cast(float, u << 16);
}
static __device__ __forceinline__ float bf_hi(unsigned u){
    return __builtin_bit_cast(float, u & 0xFFFF0000u);
}

// ---------------- CSR build ----------------

__global__ void hist_k(const int* __restrict__ dst, int* __restrict__ counts, int E){
    int e = blockIdx.x*256 + threadIdx.x;
    if (e < E) atomicAdd(&counts[dst[e]], 1);
}

__global__ void chunk_sum_k(const int* __restrict__ counts, int* __restrict__ bsum, int N){
    __shared__ int sm[256];
    int base = blockIdx.x*CHUNK;
    int t = threadIdx.x;
    int s = 0;
    #pragma unroll
    for (int j = 0; j < 4; ++j){
        int idx = base + j*256 + t;
        s += (idx < N) ? counts[idx] : 0;
    }
    sm[t] = s; __syncthreads();
    for (int off = 128; off > 0; off >>= 1){
        if (t < off) sm[t] += sm[t+off];
        __syncthreads();
    }
    if (t == 0) bsum[blockIdx.x] = sm[0];
}

// fused: per-block offset from bsum (NB<=256), chunk-local scan, row_ptr write,
// and zeroing of counts (reused as fill[] by fscatter_k).
__global__ void chunk_scan_k(int* __restrict__ counts, const int* __restrict__ bsum,
                             int* __restrict__ row_ptr, int N, int E){
    __shared__ int sm[256];
    __shared__ int co_sh;
    int t = threadIdx.x;
    int p = (t < (int)blockIdx.x) ? bsum[t] : 0;
    sm[t] = p; __syncthreads();
    for (int off = 128; off > 0; off >>= 1){
        if (t < off) sm[t] += sm[t+off];
        __syncthreads();
    }
    if (t == 0) co_sh = sm[0];
    __syncthreads();
    int co = co_sh;
    __syncthreads();                    // done with sm before reuse

    int base = blockIdx.x*CHUNK;
    int v[4]; int s = 0;
    #pragma unroll
    for (int j = 0; j < 4; ++j){
        int idx = base + t*4 + j;
        int c = (idx < N) ? counts[idx] : 0;
        v[j] = s; s += c;
    }
    sm[t] = s; __syncthreads();
    for (int off = 1; off < 256; off <<= 1){
        int add = (t >= off) ? sm[t-off] : 0;
        __syncthreads();
        sm[t] += add;
        __syncthreads();
    }
    int texcl = sm[t] - s;
    #pragma unroll
    for (int j = 0; j < 4; ++j){
        int idx = base + t*4 + j;
        if (idx < N){
            row_ptr[idx] = co + texcl + v[j];
            counts[idx] = 0;            // ready for fscatter fill
        }
    }
    if (base == 0 && t == 0) row_ptr[N] = E;
}

// bucket-scatter (src,dst) pairs into per-bucket regions of the pair array.
__global__ __launch_bounds__(256) void bscatter_k(
        const int* __restrict__ src, const int* __restrict__ dst,
        const int* __restrict__ row_ptr, int* __restrict__ bfill,
        int2* __restrict__ pairs, int E){
    __shared__ int hist[NBKT];
    __shared__ int gbase[NBKT];
    const int t = threadIdx.x;
    for (int i = t; i < NBKT; i += 256) hist[i] = 0;
    __syncthreads();
    const int e0 = blockIdx.x * 2048;
    int s[8], d[8], b[8], r[8];
    #pragma unroll
    for (int j = 0; j < 8; ++j){
        int e = e0 + j*256 + t;
        if (e < E){
            s[j] = src[e]; d[j] = dst[e];
            b[j] = d[j] >> BKT_SHIFT;
            r[j] = atomicAdd(&hist[b[j]], 1);
        }
    }
    __syncthreads();
    for (int i = t; i < NBKT; i += 256){
        int h = hist[i];
        int base = 0;
        if (h) base = atomicAdd(&bfill[i], h);
        gbase[i] = row_ptr[i << BKT_SHIFT] + base;
    }
    __syncthreads();
    #pragma unroll
    for (int j = 0; j < 8; ++j){
        int e = e0 + j*256 + t;
        if (e < E)
            pairs[gbase[b[j]] + r[j]] = make_int2(s[j], d[j]);
    }
}

// final scatter: bucket-ordered pairs -> ssorted; writes stay in a narrow window.
__global__ __launch_bounds__(256) void fscatter_k(
        const int2* __restrict__ pairs, const int* __restrict__ row_ptr,
        int* __restrict__ fill, int* __restrict__ ssorted, int E){
    const int t = threadIdx.x;
    const int e0 = blockIdx.x * 2048;
    #pragma unroll
    for (int j = 0; j < 8; ++j){
        int e = e0 + j*256 + t;
        if (e < E){
            int2 p = pairs[e];
            int pos = row_ptr[p.y] + atomicAdd(&fill[p.y], 1);
            ssorted[pos] = p.x;
        }
    }
}

// ---------------- conversions ----------------

__global__ void xconv_k(const float* __restrict__ x, unsigned short* __restrict__ xb, int n4){
    int i = blockIdx.x*256 + threadIdx.x;
    if (i < n4){
        const float4* p = (const float4*)x + i;
        float4 v = *p;
        unsigned short o0 = f2bf(v.x), o1 = f2bf(v.y), o2 = f2bf(v.z), o3 = f2bf(v.w);
        ((unsigned*)xb)[i*2]   = (unsigned)o0 | ((unsigned)o1 << 16);
        ((unsigned*)xb)[i*2+1] = (unsigned)o2 | ((unsigned)o3 << 16);
    }
}

// all three layers' weights -> combined transposed bf16 Wt[n][k] in one launch.
__global__ void prepw_all_k(const float* __restrict__ Ws0, const float* __restrict__ Wn0,
                            const float* __restrict__ Ws1, const float* __restrict__ Wn1,
                            const float* __restrict__ Ws2, const float* __restrict__ Wn2,
                            unsigned short* __restrict__ Wt0, unsigned short* __restrict__ Wt1,
                            unsigned short* __restrict__ Wt2){
    int i = blockIdx.x*256 + threadIdx.x;
    const float* Ws; const float* Wn; unsigned short* Wt; int D; int idx;
    if (i < 32768){       Ws=Ws0; Wn=Wn0; Wt=Wt0; D=128; idx=i; }
    else if (i < 65536){  Ws=Ws1; Wn=Wn1; Wt=Wt1; D=128; idx=i-32768; }
    else {                Ws=Ws2; Wn=Wn2; Wt=Wt2; D=47;  idx=i-65536; }
    int n = idx >> 7, k = idx & 127;
    float v = 0.f;
    if (n < D)        v = Ws[k*D + n];
    else if (n < 2*D) v = Wn[k*D + (n - D)];
    Wt[n*128 + k] = f2bf(v);
}

// ---------------- MFMA GEMM ----------------
// Block: 256 thr = 4 waves (2M x 2N of 64x64). Tile BM=128, BN=128 (cols of [Ws|Wn]).
// A staged in LDS via global_load_lds w/ XOR chunk swizzle; B fragments in registers.

__global__ __launch_bounds__(256) void gemm_mfma_k(
        const unsigned short* __restrict__ hb,   // [M][128] bf16
        const unsigned short* __restrict__ Wt,   // [Npad][128] bf16
        const float* __restrict__ bias,
        unsigned short* __restrict__ Y,          // [M][Dpad] bf16
        unsigned short* __restrict__ Z,          // [M][Dpad] bf16
        int M, int D, int Dpad){
    __shared__ char ldsA[128*256];               // 128 rows x 256B
    const int t = threadIdx.x;
    const int lane = t & 63;
    const int w = t >> 6;
    const int wm = w >> 1, wn = w & 1;
    const int tile = blockIdx.x * 128;
    const int cbase = blockIdx.y * 128;

    #pragma unroll
    for (int i = 0; i < 8; ++i){
        int chunkid = i*4 + w;
        int lin = chunkid*64 + lane;
        int row = lin >> 4;
        int cs  = lin & 15;
        int grow = tile + row; if (grow >= M) grow = M - 1;
        const char* src = (const char*)hb + (size_t)grow*256 + ((size_t)(cs ^ (row & 7)) << 4);
        __builtin_amdgcn_global_load_lds(
            (const __attribute__((address_space(1))) void*)src,
            (__attribute__((address_space(3))) void*)(ldsA + (size_t)chunkid*1024 + (size_t)lane*16),
            16, 0, 0);
    }

    short8 bfrag[4][4];
    {
        int ncol = cbase + wn*64;
        #pragma unroll
        for (int n = 0; n < 4; ++n){
            int wrow = ncol + n*16 + (lane & 15);
            const unsigned short* bp = Wt + (size_t)wrow*128 + ((lane >> 4) * 8);
            #pragma unroll
            for (int kk = 0; kk < 4; ++kk)
                bfrag[n][kk] = *(const short8*)(bp + kk*32);
        }
    }

    float4v acc[4][4];
    #pragma unroll
    for (int m = 0; m < 4; ++m)
        #pragma unroll
        for (int n = 0; n < 4; ++n)
            acc[m][n] = (float4v){0.f,0.f,0.f,0.f};

    __syncthreads();

    #pragma unroll
    for (int m = 0; m < 4; ++m){
        int r = wm*64 + m*16 + (lane & 15);
        #pragma unroll
        for (int kk = 0; kk < 4; ++kk){
            int c = kk*4 + (lane >> 4);
            short8 a = *(const short8*)(ldsA + (size_t)r*256 + ((size_t)(c ^ (r & 7)) << 4));
            #pragma unroll
            for (int n = 0; n < 4; ++n)
                acc[m][n] = __builtin_amdgcn_mfma_f32_16x16x32_bf16(a, bfrag[n][kk], acc[m][n], 0, 0, 0);
        }
    }

    #pragma unroll
    for (int m = 0; m < 4; ++m){
        #pragma unroll
        for (int n = 0; n < 4; ++n){
            int c = cbase + wn*64 + n*16 + (lane & 15);
            #pragma unroll
            for (int j = 0; j < 4; ++j){
                int r = tile + wm*64 + m*16 + (lane >> 4)*4 + j;
                if (r < M){
                    float v = acc[m][n][j];
                    if (c < D){
                        v += bias[c];
                        Y[(size_t)r*Dpad + c] = f2bf(v);
                    } else if (c < 2*D){
                        Z[(size_t)r*Dpad + (c - D)] = f2bf(v);
                    }
                }
            }
        }
    }
}

// ---------------- aggregation ----------------
// out = relu(Y + mean(Z[src])). One wave per node; quarter-wave (16 lanes) per edge,
// each lane loads uint4 (8 feats). 32 edges (8 loads/lane) in flight per batch.

__global__ __launch_bounds__(256) void agg128_k(
        const unsigned short* __restrict__ Yb, const unsigned short* __restrict__ Zb,
        const int* __restrict__ row_ptr, const int* __restrict__ ssorted,
        unsigned short* __restrict__ hout, int N){
    const int lane = threadIdx.x & 63;
    const int q   = lane >> 4;          // edge slot 0..3
    const int sub = lane & 15;          // feat group (8 feats = 16 B)
    const int node = blockIdx.x*4 + (threadIdx.x >> 6);
    if (node >= N) return;
    const int beg = __builtin_amdgcn_readfirstlane(row_ptr[node]);
    const int end = __builtin_amdgcn_readfirstlane(row_ptr[node+1]);
    const float inv = 1.0f / fmaxf((float)(end - beg), 1.0f);
    const char* zc = (const char*)Zb;
    const unsigned boff = (unsigned)(sub*16);
    f32x2 a0={0.f,0.f}, a1={0.f,0.f}, a2={0.f,0.f}, a3={0.f,0.f};
    for (int e = beg; e < end; e += 32){
        int s[8];
        #pragma unroll
        for (int j = 0; j < 8; ++j){
            int ei = e + 4*j + q;
            int ec = ei < end ? ei : end - 1;
            s[j] = ssorted[ec];
        }
        uint4 u[8];
        #pragma unroll
        for (int j = 0; j < 8; ++j)
            u[j] = *(const uint4*)(zc + ((unsigned)s[j]*256u + boff));
        #pragma unroll
        for (int j = 0; j < 8; ++j){
            if (e + 4*j + q < end){
                a0 += (f32x2){ bf_lo(u[j].x), bf_hi(u[j].x) };
                a1 += (f32x2){ bf_lo(u[j].y), bf_hi(u[j].y) };
                a2 += (f32x2){ bf_lo(u[j].z), bf_hi(u[j].z) };
                a3 += (f32x2){ bf_lo(u[j].w), bf_hi(u[j].w) };
            }
        }
    }
    // reduce across the 4 edge slots (lane bits 4,5)
    a0.x += __shfl_xor(a0.x,16,64); a0.x += __shfl_xor(a0.x,32,64);
    a0.y += __shfl_xor(a0.y,16,64); a0.y += __shfl_xor(a0.y,32,64);
    a1.x += __shfl_xor(a1.x,16,64); a1.x += __shfl_xor(a1.x,32,64);
    a1.y += __shfl_xor(a1.y,16,64); a1.y += __shfl_xor(a1.y,32,64);
    a2.x += __shfl_xor(a2.x,16,64); a2.x += __shfl_xor(a2.x,32,64);
    a2.y += __shfl_xor(a2.y,16,64); a2.y += __shfl_xor(a2.y,32,64);
    a3.x += __shfl_xor(a3.x,16,64); a3.x += __shfl_xor(a3.x,32,64);
    a3.y += __shfl_xor(a3.y,16,64); a3.y += __shfl_xor(a3.y,32,64);
    if (q == 0){
        uint4 yu = *(const uint4*)((const char*)Yb + (size_t)node*256 + sub*16);
        float r0 = fmaxf(bf_lo(yu.x) + a0.x*inv, 0.f);
        float r1 = fmaxf(bf_hi(yu.x) + a0.y*inv, 0.f);
        float r2 = fmaxf(bf_lo(yu.y) + a1.x*inv, 0.f);
        float r3 = fmaxf(bf_hi(yu.y) + a1.y*inv, 0.f);
        float r4 = fmaxf(bf_lo(yu.z) + a2.x*inv, 0.f);
        float r5 = fmaxf(bf_hi(yu.z) + a2.y*inv, 0.f);
        float r6 = fmaxf(bf_lo(yu.w) + a3.x*inv, 0.f);
        float r7 = fmaxf(bf_hi(yu.w) + a3.y*inv, 0.f);
        uint4 o;
        o.x = (unsigned)f2bf(r0) | ((unsigned)f2bf(r1) << 16);
        o.y = (unsigned)f2bf(r2) | ((unsigned)f2bf(r3) << 16);
        o.z = (unsigned)f2bf(r4) | ((unsigned)f2bf(r5) << 16);
        o.w = (unsigned)f2bf(r6) | ((unsigned)f2bf(r7) << 16);
        *(uint4*)((char*)hout + (size_t)node*256 + sub*16) = o;
    }
}

// final layer: D=47 (Dpad=48), f32 out, no relu. Quarter-wave per edge,
// 12 active lanes x 4 feats (uint2); 32 edges in flight per batch.
__global__ __launch_bounds__(256) void aggfin_k(
        const unsigned short* __restrict__ Yb, const unsigned short* __restrict__ Zb,
        const int* __restrict__ row_ptr, const int* __restrict__ ssorted,
        float* __restrict__ out, int N){
    const int lane = threadIdx.x & 63;
    const int q   = lane >> 4;          // edge slot 0..3
    const int sub = lane & 15;          // feat group, active if <12
    const int node = blockIdx.x*4 + (threadIdx.x >> 6);
    if (node >= N) return;
    const int beg = __builtin_amdgcn_readfirstlane(row_ptr[node]);
    const int end = __builtin_amdgcn_readfirstlane(row_ptr[node+1]);
    const float inv = 1.0f / fmaxf((float)(end - beg), 1.0f);
    const char* zc = (const char*)Zb;
    const bool act = (sub < 12);
    const unsigned boff = (unsigned)(sub*8);
    f32x2 acc0 = {0.f,0.f}, acc1 = {0.f,0.f};
    for (int e = beg; e < end; e += 32){
        int s[8];
        #pragma unroll
        for (int j = 0; j < 8; ++j){
            int ei = e + 4*j + q;
            int ec = ei < end ? ei : end - 1;
            s[j] = ssorted[ec];
        }
        #pragma unroll
        for (int j = 0; j < 8; ++j){
            if (act){
                uint2 u = *(const uint2*)(zc + ((unsigned)s[j]*96u + boff));
                if (e + 4*j + q < end){
                    acc0 += (f32x2){ bf_lo(u.x), bf_lo(u.y) };
                    acc1 += (f32x2){ bf_hi(u.x), bf_hi(u.y) };
                }
            }
        }
    }
    acc0.x += __shfl_xor(acc0.x, 16, 64); acc0.x += __shfl_xor(acc0.x, 32, 64);
    acc0.y += __shfl_xor(acc0.y, 16, 64); acc0.y += __shfl_xor(acc0.y, 32, 64);
    acc1.x += __shfl_xor(acc1.x, 16, 64); acc1.x += __shfl_xor(acc1.x, 32, 64);
    acc1.y += __shfl_xor(acc1.y, 16, 64); acc1.y += __shfl_xor(acc1.y, 32, 64);
    if (q == 0 && act){
        uint2 yu = *(const uint2*)((const char*)Yb + (size_t)node*96 + sub*8);
        float r0 = bf_lo(yu.x) + acc0.x*inv;
        float r1 = bf_hi(yu.x) + acc1.x*inv;
        float r2 = bf_lo(yu.y) + acc0.y*inv;
        float r3 = bf_hi(yu.y) + acc1.y*inv;
        int f = 4*sub;
        size_t o = (size_t)node*47 + f;
        out[o]   = r0;
        out[o+1] = r1;
        out[o+2] = r2;
        if (f + 3 < 47) out[o+3] = r3;
    }
}

// ---------------- launch ----------------

extern "C" void kernel_launch(void* const* d_in, const int* in_sizes, int n_in,
                              void* d_out, int out_size, void* d_ws, size_t ws_size,
                              hipStream_t stream){
    const float* x   = (const float*)d_in[0];
    const int*   src = (const int*)  d_in[1];
    const int*   dstv= (const int*)  d_in[2];
    const float* Ws0 = (const float*)d_in[3];
    const float* Wn0 = (const float*)d_in[4];
    const float* b0  = (const float*)d_in[5];
    const float* Ws1 = (const float*)d_in[6];
    const float* Wn1 = (const float*)d_in[7];
    const float* b1  = (const float*)d_in[8];
    const float* Ws2 = (const float*)d_in[9];
    const float* Wn2 = (const float*)d_in[10];
    const float* b2  = (const float*)d_in[11];
    float* out = (float*)d_out;
    const int N = NN, E = NE;

    char* w = (char*)d_ws;
    size_t off = 0;
    auto alloc = [&](size_t bytes)->char*{
        char* p = w + off; off += (bytes + 255) & ~(size_t)255; return p;
    };
    int*   cbuf    = (int*)  alloc((size_t)(N + NBKT)*4);   // counts | bfill, one memset
    int*   counts  = cbuf;
    int*   bfill   = cbuf + N;
    int*   row_ptr = (int*)  alloc((size_t)(N+1)*4);
    int*   ssorted = (int*)  alloc((size_t)E*4);
    int*   bsum    = (int*)  alloc(4096);
    int2*  pairs   = (int2*) alloc((size_t)E*8);
    unsigned short* xb  = (unsigned short*)alloc((size_t)N*F*2);
    unsigned short* hA  = (unsigned short*)alloc((size_t)N*F*2);
    unsigned short* hB  = (unsigned short*)alloc((size_t)N*F*2);
    unsigned short* Yb  = (unsigned short*)alloc((size_t)N*F*2);
    unsigned short* Zb  = (unsigned short*)alloc((size_t)N*F*2);
    unsigned short* Wt0 = (unsigned short*)alloc((size_t)256*128*2);
    unsigned short* Wt1 = (unsigned short*)alloc((size_t)256*128*2);
    unsigned short* Wt2 = (unsigned short*)alloc((size_t)128*128*2);
    (void)ws_size; (void)n_in; (void)in_sizes; (void)out_size;

    const int NB = (N + CHUNK - 1)/CHUNK;   // 98 <= 256 required by chunk_scan_k
    const int GE = (E + 2047)/2048;

    hipMemsetAsync(cbuf, 0, (size_t)(N + NBKT)*4, stream);
    hist_k      <<<(E+255)/256, 256, 0, stream>>>(dstv, counts, E);
    chunk_sum_k <<<NB, 256, 0, stream>>>(counts, bsum, N);
    chunk_scan_k<<<NB, 256, 0, stream>>>(counts, bsum, row_ptr, N, E);
    bscatter_k  <<<GE, 256, 0, stream>>>(src, dstv, row_ptr, bfill, pairs, E);
    fscatter_k  <<<GE, 256, 0, stream>>>(pairs, row_ptr, counts, ssorted, E);

    xconv_k<<<(N*F/4 + 255)/256, 256, 0, stream>>>(x, xb, N*F/4);
    prepw_all_k<<<320, 256, 0, stream>>>(Ws0, Wn0, Ws1, Wn1, Ws2, Wn2, Wt0, Wt1, Wt2);

    const int GM = (N + 127)/128;
    const int GA = (N + 3)/4;

    gemm_mfma_k<<<dim3(GM,2), 256, 0, stream>>>(xb, Wt0, b0, Yb, Zb, N, 128, 128);
    agg128_k   <<<GA, 256, 0, stream>>>(Yb, Zb, row_ptr, ssorted, hA, N);
    gemm_mfma_k<<<dim3(GM,2), 256, 0, stream>>>(hA, Wt1, b1, Yb, Zb, N, 128, 128);
    agg128_k   <<<GA, 256, 0, stream>>>(Yb, Zb, row_ptr, ssorted, hB, N);
    gemm_mfma_k<<<dim3(GM,1), 256, 0, stream>>>(hB, Wt2, b2, Yb, Zb, N, 47, 48);
    aggfin_k   <<<GA, 256, 0, stream>>>(Yb, Zb, row_ptr, ssorted, out, N);
}

// Round 7
// 431.416 us; speedup vs baseline: 2.6686x; 1.1260x over previous
//
#include <hip/hip_runtime.h>
#include <cstdint>
#include <cstddef>

static const int NN = 100000;
static const int NE = 1600000;
static const int F  = 128;       // K dim (feature width)
static const int CHUNK = 1024;   // scan chunk
static const int BKT_SHIFT = 9;  // 512 nodes per bucket
static const int BNODES = 1 << BKT_SHIFT;
static const int NBKT = (NN + BNODES - 1) >> BKT_SHIFT;   // 196 (must be <= 256)
static const int SRC_BITS = 17;  // 100000 < 2^17
static const unsigned SRC_MASK = (1u << SRC_BITS) - 1u;

typedef __attribute__((ext_vector_type(8))) short short8;
typedef __attribute__((ext_vector_type(4))) float float4v;
typedef __attribute__((ext_vector_type(2))) float f32x2;

static __device__ __forceinline__ unsigned short f2bf(float f){
    unsigned u = __builtin_bit_cast(unsigned, f);
    unsigned r = (u + 0x7FFFu + ((u >> 16) & 1u)) >> 16;
    return (unsigned short)r;
}
static __device__ __forceinline__ float bf_lo(unsigned u){
    return __builtin_bit_cast(float, u << 16);
}
static __device__ __forceinline__ float bf_hi(unsigned u){
    return __builtin_bit_cast(float, u & 0xFFFF0000u);
}

// ---------------- CSR build ----------------

__global__ void hist_k(const int* __restrict__ dst, int* __restrict__ counts, int E){
    int e = blockIdx.x*256 + threadIdx.x;
    if (e < E) atomicAdd(&counts[dst[e]], 1);
}

__global__ void chunk_sum_k(const int* __restrict__ counts, int* __restrict__ bsum, int N){
    __shared__ int sm[256];
    int base = blockIdx.x*CHUNK;
    int t = threadIdx.x;
    int s = 0;
    #pragma unroll
    for (int j = 0; j < 4; ++j){
        int idx = base + j*256 + t;
        s += (idx < N) ? counts[idx] : 0;
    }
    sm[t] = s; __syncthreads();
    for (int off = 128; off > 0; off >>= 1){
        if (t < off) sm[t] += sm[t+off];
        __syncthreads();
    }
    if (t == 0) bsum[blockIdx.x] = sm[0];
}

// fused: per-block offset from bsum (NB<=256), chunk-local scan, row_ptr write.
__global__ void chunk_scan_k(const int* __restrict__ counts, const int* __restrict__ bsum,
                             int* __restrict__ row_ptr, int N, int E){
    __shared__ int sm[256];
    __shared__ int co_sh;
    int t = threadIdx.x;
    int p = (t < (int)blockIdx.x) ? bsum[t] : 0;
    sm[t] = p; __syncthreads();
    for (int off = 128; off > 0; off >>= 1){
        if (t < off) sm[t] += sm[t+off];
        __syncthreads();
    }
    if (t == 0) co_sh = sm[0];
    __syncthreads();
    int co = co_sh;
    __syncthreads();                    // done with sm before reuse

    int base = blockIdx.x*CHUNK;
    int v[4]; int s = 0;
    #pragma unroll
    for (int j = 0; j < 4; ++j){
        int idx = base + t*4 + j;
        int c = (idx < N) ? counts[idx] : 0;
        v[j] = s; s += c;
    }
    sm[t] = s; __syncthreads();
    for (int off = 1; off < 256; off <<= 1){
        int add = (t >= off) ? sm[t-off] : 0;
        __syncthreads();
        sm[t] += add;
        __syncthreads();
    }
    int texcl = sm[t] - s;
    #pragma unroll
    for (int j = 0; j < 4; ++j){
        int idx = base + t*4 + j;
        if (idx < N) row_ptr[idx] = co + texcl + v[j];
    }
    if (base == 0 && t == 0) row_ptr[N] = E;
}

// bucket-scatter packed (src | dlocal<<17) into per-bucket regions of pk[].
__global__ __launch_bounds__(256) void bscatter_k(
        const int* __restrict__ src, const int* __restrict__ dst,
        const int* __restrict__ row_ptr, int* __restrict__ bfill,
        unsigned* __restrict__ pk, int E){
    __shared__ int hist[NBKT];
    __shared__ int gbase[NBKT];
    const int t = threadIdx.x;
    for (int i = t; i < NBKT; i += 256) hist[i] = 0;
    __syncthreads();
    const int e0 = blockIdx.x * 2048;
    int s[8], d[8], b[8], r[8];
    #pragma unroll
    for (int j = 0; j < 8; ++j){
        int e = e0 + j*256 + t;
        if (e < E){
            s[j] = src[e]; d[j] = dst[e];
            b[j] = d[j] >> BKT_SHIFT;
            r[j] = atomicAdd(&hist[b[j]], 1);
        }
    }
    __syncthreads();
    for (int i = t; i < NBKT; i += 256){
        int h = hist[i];
        int base = 0;
        if (h) base = atomicAdd(&bfill[i], h);
        gbase[i] = row_ptr[i << BKT_SHIFT] + base;
    }
    __syncthreads();
    #pragma unroll
    for (int j = 0; j < 8; ++j){
        int e = e0 + j*256 + t;
        if (e < E)
            pk[gbase[b[j]] + r[j]] =
                (unsigned)s[j] | ((unsigned)(d[j] & (BNODES-1)) << SRC_BITS);
    }
}

// per-bucket counting sort, one block per bucket. Offsets come from row_ptr;
// fill counters live in LDS; output range is block-owned and contiguous.
__global__ __launch_bounds__(1024) void sort_k(
        const unsigned* __restrict__ pk, const int* __restrict__ row_ptr,
        int* __restrict__ ssorted, int N){
    __shared__ int offs[BNODES];
    __shared__ int fill[BNODES];
    const int b  = blockIdx.x;
    const int n0 = b << BKT_SHIFT;
    const int t  = threadIdx.x;
    const int nend = min(n0 + BNODES, N);
    const int rbeg = row_ptr[n0];
    const int rend = row_ptr[nend];
    for (int i = t; i < BNODES; i += 1024){
        int node = n0 + i;
        offs[i] = (node < N) ? row_ptr[node] : rend;
        fill[i] = 0;
    }
    __syncthreads();
    for (int e = rbeg + t; e < rend; e += 1024){
        unsigned p = pk[e];
        int srcv = (int)(p & SRC_MASK);
        int dl   = (int)(p >> SRC_BITS);
        int pos  = offs[dl] + atomicAdd(&fill[dl], 1);
        ssorted[pos] = srcv;
    }
}

// ---------------- conversions ----------------

__global__ void xconv_k(const float* __restrict__ x, unsigned short* __restrict__ xb, int n4){
    int i = blockIdx.x*256 + threadIdx.x;
    if (i < n4){
        const float4* p = (const float4*)x + i;
        float4 v = *p;
        unsigned short o0 = f2bf(v.x), o1 = f2bf(v.y), o2 = f2bf(v.z), o3 = f2bf(v.w);
        ((unsigned*)xb)[i*2]   = (unsigned)o0 | ((unsigned)o1 << 16);
        ((unsigned*)xb)[i*2+1] = (unsigned)o2 | ((unsigned)o3 << 16);
    }
}

// all three layers' weights -> combined transposed bf16 Wt[n][k] in one launch.
__global__ void prepw_all_k(const float* __restrict__ Ws0, const float* __restrict__ Wn0,
                            const float* __restrict__ Ws1, const float* __restrict__ Wn1,
                            const float* __restrict__ Ws2, const float* __restrict__ Wn2,
                            unsigned short* __restrict__ Wt0, unsigned short* __restrict__ Wt1,
                            unsigned short* __restrict__ Wt2){
    int i = blockIdx.x*256 + threadIdx.x;
    const float* Ws; const float* Wn; unsigned short* Wt; int D; int idx;
    if (i < 32768){       Ws=Ws0; Wn=Wn0; Wt=Wt0; D=128; idx=i; }
    else if (i < 65536){  Ws=Ws1; Wn=Wn1; Wt=Wt1; D=128; idx=i-32768; }
    else {                Ws=Ws2; Wn=Wn2; Wt=Wt2; D=47;  idx=i-65536; }
    int n = idx >> 7, k = idx & 127;
    float v = 0.f;
    if (n < D)        v = Ws[k*D + n];
    else if (n < 2*D) v = Wn[k*D + (n - D)];
    Wt[n*128 + k] = f2bf(v);
}

// ---------------- MFMA GEMM ----------------
// Block: 256 thr = 4 waves (2M x 2N of 64x64). Tile BM=128, BN=128 (cols of [Ws|Wn]).
// A staged in LDS via global_load_lds w/ XOR chunk swizzle; B fragments in registers.

__global__ __launch_bounds__(256) void gemm_mfma_k(
        const unsigned short* __restrict__ hb,   // [M][128] bf16
        const unsigned short* __restrict__ Wt,   // [Npad][128] bf16
        const float* __restrict__ bias,
        unsigned short* __restrict__ Y,          // [M][Dpad] bf16
        unsigned short* __restrict__ Z,          // [M][Dpad] bf16
        int M, int D, int Dpad){
    __shared__ char ldsA[128*256];               // 128 rows x 256B
    const int t = threadIdx.x;
    const int lane = t & 63;
    const int w = t >> 6;
    const int wm = w >> 1, wn = w & 1;
    const int tile = blockIdx.x * 128;
    const int cbase = blockIdx.y * 128;

    #pragma unroll
    for (int i = 0; i < 8; ++i){
        int chunkid = i*4 + w;
        int lin = chunkid*64 + lane;
        int row = lin >> 4;
        int cs  = lin & 15;
        int grow = tile + row; if (grow >= M) grow = M - 1;
        const char* src = (const char*)hb + (size_t)grow*256 + ((size_t)(cs ^ (row & 7)) << 4);
        __builtin_amdgcn_global_load_lds(
            (const __attribute__((address_space(1))) void*)src,
            (__attribute__((address_space(3))) void*)(ldsA + (size_t)chunkid*1024 + (size_t)lane*16),
            16, 0, 0);
    }

    short8 bfrag[4][4];
    {
        int ncol = cbase + wn*64;
        #pragma unroll
        for (int n = 0; n < 4; ++n){
            int wrow = ncol + n*16 + (lane & 15);
            const unsigned short* bp = Wt + (size_t)wrow*128 + ((lane >> 4) * 8);
            #pragma unroll
            for (int kk = 0; kk < 4; ++kk)
                bfrag[n][kk] = *(const short8*)(bp + kk*32);
        }
    }

    float4v acc[4][4];
    #pragma unroll
    for (int m = 0; m < 4; ++m)
        #pragma unroll
        for (int n = 0; n < 4; ++n)
            acc[m][n] = (float4v){0.f,0.f,0.f,0.f};

    __syncthreads();

    #pragma unroll
    for (int m = 0; m < 4; ++m){
        int r = wm*64 + m*16 + (lane & 15);
        #pragma unroll
        for (int kk = 0; kk < 4; ++kk){
            int c = kk*4 + (lane >> 4);
            short8 a = *(const short8*)(ldsA + (size_t)r*256 + ((size_t)(c ^ (r & 7)) << 4));
            #pragma unroll
            for (int n = 0; n < 4; ++n)
                acc[m][n] = __builtin_amdgcn_mfma_f32_16x16x32_bf16(a, bfrag[n][kk], acc[m][n], 0, 0, 0);
        }
    }

    #pragma unroll
    for (int m = 0; m < 4; ++m){
        #pragma unroll
        for (int n = 0; n < 4; ++n){
            int c = cbase + wn*64 + n*16 + (lane & 15);
            #pragma unroll
            for (int j = 0; j < 4; ++j){
                int r = tile + wm*64 + m*16 + (lane >> 4)*4 + j;
                if (r < M){
                    float v = acc[m][n][j];
                    if (c < D){
                        v += bias[c];
                        Y[(size_t)r*Dpad + c] = f2bf(v);
                    } else if (c < 2*D){
                        Z[(size_t)r*Dpad + (c - D)] = f2bf(v);
                    }
                }
            }
        }
    }
}

// ---------------- aggregation ----------------
// out = relu(Y + mean(Z[src])). One wave per node; quarter-wave (16 lanes) per edge,
// each lane loads uint4 (8 feats). 32 edges (8 loads/lane) in flight per batch.

__global__ __launch_bounds__(256) void agg128_k(
        const unsigned short* __restrict__ Yb, const unsigned short* __restrict__ Zb,
        const int* __restrict__ row_ptr, const int* __restrict__ ssorted,
        unsigned short* __restrict__ hout, int N){
    const int lane = threadIdx.x & 63;
    const int q   = lane >> 4;          // edge slot 0..3
    const int sub = lane & 15;          // feat group (8 feats = 16 B)
    const int node = blockIdx.x*4 + (threadIdx.x >> 6);
    if (node >= N) return;
    const int beg = __builtin_amdgcn_readfirstlane(row_ptr[node]);
    const int end = __builtin_amdgcn_readfirstlane(row_ptr[node+1]);
    const float inv = 1.0f / fmaxf((float)(end - beg), 1.0f);
    const char* zc = (const char*)Zb;
    const unsigned boff = (unsigned)(sub*16);
    f32x2 a0={0.f,0.f}, a1={0.f,0.f}, a2={0.f,0.f}, a3={0.f,0.f};
    for (int e = beg; e < end; e += 32){
        int s[8];
        #pragma unroll
        for (int j = 0; j < 8; ++j){
            int ei = e + 4*j + q;
            int ec = ei < end ? ei : end - 1;
            s[j] = ssorted[ec];
        }
        uint4 u[8];
        #pragma unroll
        for (int j = 0; j < 8; ++j)
            u[j] = *(const uint4*)(zc + ((unsigned)s[j]*256u + boff));
        #pragma unroll
        for (int j = 0; j < 8; ++j){
            if (e + 4*j + q < end){
                a0 += (f32x2){ bf_lo(u[j].x), bf_hi(u[j].x) };
                a1 += (f32x2){ bf_lo(u[j].y), bf_hi(u[j].y) };
                a2 += (f32x2){ bf_lo(u[j].z), bf_hi(u[j].z) };
                a3 += (f32x2){ bf_lo(u[j].w), bf_hi(u[j].w) };
            }
        }
    }
    // reduce across the 4 edge slots (lane bits 4,5)
    a0.x += __shfl_xor(a0.x,16,64); a0.x += __shfl_xor(a0.x,32,64);
    a0.y += __shfl_xor(a0.y,16,64); a0.y += __shfl_xor(a0.y,32,64);
    a1.x += __shfl_xor(a1.x,16,64); a1.x += __shfl_xor(a1.x,32,64);
    a1.y += __shfl_xor(a1.y,16,64); a1.y += __shfl_xor(a1.y,32,64);
    a2.x += __shfl_xor(a2.x,16,64); a2.x += __shfl_xor(a2.x,32,64);
    a2.y += __shfl_xor(a2.y,16,64); a2.y += __shfl_xor(a2.y,32,64);
    a3.x += __shfl_xor(a3.x,16,64); a3.x += __shfl_xor(a3.x,32,64);
    a3.y += __shfl_xor(a3.y,16,64); a3.y += __shfl_xor(a3.y,32,64);
    if (q == 0){
        uint4 yu = *(const uint4*)((const char*)Yb + (size_t)node*256 + sub*16);
        float r0 = fmaxf(bf_lo(yu.x) + a0.x*inv, 0.f);
        float r1 = fmaxf(bf_hi(yu.x) + a0.y*inv, 0.f);
        float r2 = fmaxf(bf_lo(yu.y) + a1.x*inv, 0.f);
        float r3 = fmaxf(bf_hi(yu.y) + a1.y*inv, 0.f);
        float r4 = fmaxf(bf_lo(yu.z) + a2.x*inv, 0.f);
        float r5 = fmaxf(bf_hi(yu.z) + a2.y*inv, 0.f);
        float r6 = fmaxf(bf_lo(yu.w) + a3.x*inv, 0.f);
        float r7 = fmaxf(bf_hi(yu.w) + a3.y*inv, 0.f);
        uint4 o;
        o.x = (unsigned)f2bf(r0) | ((unsigned)f2bf(r1) << 16);
        o.y = (unsigned)f2bf(r2) | ((unsigned)f2bf(r3) << 16);
        o.z = (unsigned)f2bf(r4) | ((unsigned)f2bf(r5) << 16);
        o.w = (unsigned)f2bf(r6) | ((unsigned)f2bf(r7) << 16);
        *(uint4*)((char*)hout + (size_t)node*256 + sub*16) = o;
    }
}

// final layer: D=47 (Dpad=48), f32 out, no relu. Quarter-wave per edge,
// 12 active lanes x 4 feats (uint2); 32 edges in flight per batch.
__global__ __launch_bounds__(256) void aggfin_k(
        const unsigned short* __restrict__ Yb, const unsigned short* __restrict__ Zb,
        const int* __restrict__ row_ptr, const int* __restrict__ ssorted,
        float* __restrict__ out, int N){
    const int lane = threadIdx.x & 63;
    const int q   = lane >> 4;          // edge slot 0..3
    const int sub = lane & 15;          // feat group, active if <12
    const int node = blockIdx.x*4 + (threadIdx.x >> 6);
    if (node >= N) return;
    const int beg = __builtin_amdgcn_readfirstlane(row_ptr[node]);
    const int end = __builtin_amdgcn_readfirstlane(row_ptr[node+1]);
    const float inv = 1.0f / fmaxf((float)(end - beg), 1.0f);
    const char* zc = (const char*)Zb;
    const bool act = (sub < 12);
    const unsigned boff = (unsigned)(sub*8);
    f32x2 acc0 = {0.f,0.f}, acc1 = {0.f,0.f};
    for (int e = beg; e < end; e += 32){
        int s[8];
        #pragma unroll
        for (int j = 0; j < 8; ++j){
            int ei = e + 4*j + q;
            int ec = ei < end ? ei : end - 1;
            s[j] = ssorted[ec];
        }
        #pragma unroll
        for (int j = 0; j < 8; ++j){
            if (act){
                uint2 u = *(const uint2*)(zc + ((unsigned)s[j]*96u + boff));
                if (e + 4*j + q < end){
                    acc0 += (f32x2){ bf_lo(u.x), bf_lo(u.y) };
                    acc1 += (f32x2){ bf_hi(u.x), bf_hi(u.y) };
                }
            }
        }
    }
    acc0.x += __shfl_xor(acc0.x, 16, 64); acc0.x += __shfl_xor(acc0.x, 32, 64);
    acc0.y += __shfl_xor(acc0.y, 16, 64); acc0.y += __shfl_xor(acc0.y, 32, 64);
    acc1.x += __shfl_xor(acc1.x, 16, 64); acc1.x += __shfl_xor(acc1.x, 32, 64);
    acc1.y += __shfl_xor(acc1.y, 16, 64); acc1.y += __shfl_xor(acc1.y, 32, 64);
    if (q == 0 && act){
        uint2 yu = *(const uint2*)((const char*)Yb + (size_t)node*96 + sub*8);
        float r0 = bf_lo(yu.x) + acc0.x*inv;
        float r1 = bf_hi(yu.x) + acc1.x*inv;
        float r2 = bf_lo(yu.y) + acc0.y*inv;
        float r3 = bf_hi(yu.y) + acc1.y*inv;
        int f = 4*sub;
        size_t o = (size_t)node*47 + f;
        out[o]   = r0;
        out[o+1] = r1;
        out[o+2] = r2;
        if (f + 3 < 47) out[o+3] = r3;
    }
}

// ---------------- launch ----------------

extern "C" void kernel_launch(void* const* d_in, const int* in_sizes, int n_in,
                              void* d_out, int out_size, void* d_ws, size_t ws_size,
                              hipStream_t stream){
    const float* x   = (const float*)d_in[0];
    const int*   src = (const int*)  d_in[1];
    const int*   dstv= (const int*)  d_in[2];
    const float* Ws0 = (const float*)d_in[3];
    const float* Wn0 = (const float*)d_in[4];
    const float* b0  = (const float*)d_in[5];
    const float* Ws1 = (const float*)d_in[6];
    const float* Wn1 = (const float*)d_in[7];
    const float* b1  = (const float*)d_in[8];
    const float* Ws2 = (const float*)d_in[9];
    const float* Wn2 = (const float*)d_in[10];
    const float* b2  = (const float*)d_in[11];
    float* out = (float*)d_out;
    const int N = NN, E = NE;

    char* w = (char*)d_ws;
    size_t off = 0;
    auto alloc = [&](size_t bytes)->char*{
        char* p = w + off; off += (bytes + 255) & ~(size_t)255; return p;
    };
    int*   cbuf    = (int*)  alloc((size_t)(N + NBKT)*4);   // counts | bfill, one memset
    int*   counts  = cbuf;
    int*   bfill   = cbuf + N;
    int*   row_ptr = (int*)  alloc((size_t)(N+1)*4);
    int*   ssorted = (int*)  alloc((size_t)E*4);
    int*   bsum    = (int*)  alloc(4096);
    unsigned* pk   = (unsigned*)alloc((size_t)E*4);
    unsigned short* xb  = (unsigned short*)alloc((size_t)N*F*2);
    unsigned short* hA  = (unsigned short*)alloc((size_t)N*F*2);
    unsigned short* hB  = (unsigned short*)alloc((size_t)N*F*2);
    unsigned short* Yb  = (unsigned short*)alloc((size_t)N*F*2);
    unsigned short* Zb  = (unsigned short*)alloc((size_t)N*F*2);
    unsigned short* Wt0 = (unsigned short*)alloc((size_t)256*128*2);
    unsigned short* Wt1 = (unsigned short*)alloc((size_t)256*128*2);
    unsigned short* Wt2 = (unsigned short*)alloc((size_t)128*128*2);
    (void)ws_size; (void)n_in; (void)in_sizes; (void)out_size;

    const int NB = (N + CHUNK - 1)/CHUNK;   // 98 <= 256 required by chunk_scan_k
    const int GE = (E + 2047)/2048;

    hipMemsetAsync(cbuf, 0, (size_t)(N + NBKT)*4, stream);
    hist_k      <<<(E+255)/256, 256, 0, stream>>>(dstv, counts, E);
    chunk_sum_k <<<NB, 256, 0, stream>>>(counts, bsum, N);
    chunk_scan_k<<<NB, 256, 0, stream>>>(counts, bsum, row_ptr, N, E);
    bscatter_k  <<<GE, 256, 0, stream>>>(src, dstv, row_ptr, bfill, pk, E);
    sort_k      <<<NBKT, 1024, 0, stream>>>(pk, row_ptr, ssorted, N);

    xconv_k<<<(N*F/4 + 255)/256, 256, 0, stream>>>(x, xb, N*F/4);
    prepw_all_k<<<320, 256, 0, stream>>>(Ws0, Wn0, Ws1, Wn1, Ws2, Wn2, Wt0, Wt1, Wt2);

    const int GM = (N + 127)/128;
    const int GA = (N + 3)/4;

    gemm_mfma_k<<<dim3(GM,2), 256, 0, stream>>>(xb, Wt0, b0, Yb, Zb, N, 128, 128);
    agg128_k   <<<GA, 256, 0, stream>>>(Yb, Zb, row_ptr, ssorted, hA, N);
    gemm_mfma_k<<<dim3(GM,2), 256, 0, stream>>>(hA, Wt1, b1, Yb, Zb, N, 128, 128);
    agg128_k   <<<GA, 256, 0, stream>>>(Yb, Zb, row_ptr, ssorted, hB, N);
    gemm_mfma_k<<<dim3(GM,1), 256, 0, stream>>>(hB, Wt2, b2, Yb, Zb, N, 47, 48);
    aggfin_k   <<<GA, 256, 0, stream>>>(Yb, Zb, row_ptr, ssorted, out, N);
}

// Round 8
// 388.699 us; speedup vs baseline: 2.9619x; 1.1099x over previous
//
#include <hip/hip_runtime.h>
#include <cstdint>
#include <cstddef>

static const int NN = 100000;
static const int NE = 1600000;
static const int F  = 128;       // K dim (feature width)
static const int BKT_SHIFT = 9;  // 512 nodes per bucket
static const int BNODES = 1 << BKT_SHIFT;
static const int NBKT = (NN + BNODES - 1) >> BKT_SHIFT;   // 196 (must be <= 256)
static const int SRC_BITS = 17;  // 100000 < 2^17
static const unsigned SRC_MASK = (1u << SRC_BITS) - 1u;

typedef __attribute__((ext_vector_type(8))) short short8;
typedef __attribute__((ext_vector_type(4))) float float4v;
typedef __attribute__((ext_vector_type(2))) float f32x2;

static __device__ __forceinline__ unsigned short f2bf(float f){
    unsigned u = __builtin_bit_cast(unsigned, f);
    unsigned r = (u + 0x7FFFu + ((u >> 16) & 1u)) >> 16;
    return (unsigned short)r;
}
static __device__ __forceinline__ float bf_lo(unsigned u){
    return __builtin_bit_cast(float, u << 16);
}
static __device__ __forceinline__ float bf_hi(unsigned u){
    return __builtin_bit_cast(float, u & 0xFFFF0000u);
}

// ---------------- CSR build (bucketed, no global per-node histogram) ----------------

// per-block LDS histogram of buckets -> 196 global counters
__global__ __launch_bounds__(256) void bhist_k(const int* __restrict__ dst,
                                               int* __restrict__ bcnt, int E){
    __shared__ int h[NBKT];
    const int t = threadIdx.x;
    for (int i = t; i < NBKT; i += 256) h[i] = 0;
    __syncthreads();
    const int e0 = blockIdx.x * 2048;
    #pragma unroll
    for (int j = 0; j < 8; ++j){
        int e = e0 + j*256 + t;
        if (e < E) atomicAdd(&h[dst[e] >> BKT_SHIFT], 1);
    }
    __syncthreads();
    for (int i = t; i < NBKT; i += 256)
        if (h[i]) atomicAdd(&bcnt[i], h[i]);
}

// one block: exclusive scan of 196 bucket counts -> bptr[197]
__global__ __launch_bounds__(256) void bscan_k(const int* __restrict__ bcnt,
                                               int* __restrict__ bptr){
    __shared__ int sm[256];
    int t = threadIdx.x;
    int v = (t < NBKT) ? bcnt[t] : 0;
    sm[t] = v; __syncthreads();
    for (int off = 1; off < 256; off <<= 1){
        int add = (t >= off) ? sm[t-off] : 0;
        __syncthreads();
        sm[t] += add;
        __syncthreads();
    }
    if (t < NBKT) bptr[t+1] = sm[t];
    if (t == 0)   bptr[0] = 0;
}

// bucket-scatter packed (src | dlocal<<17) into per-bucket regions of pk[].
__global__ __launch_bounds__(256) void bscatter_k(
        const int* __restrict__ src, const int* __restrict__ dst,
        const int* __restrict__ bptr, int* __restrict__ bfill,
        unsigned* __restrict__ pk, int E){
    __shared__ int hist[NBKT];
    __shared__ int gbase[NBKT];
    const int t = threadIdx.x;
    for (int i = t; i < NBKT; i += 256) hist[i] = 0;
    __syncthreads();
    const int e0 = blockIdx.x * 2048;
    int s[8], d[8], b[8], r[8];
    #pragma unroll
    for (int j = 0; j < 8; ++j){
        int e = e0 + j*256 + t;
        if (e < E){
            s[j] = src[e]; d[j] = dst[e];
            b[j] = d[j] >> BKT_SHIFT;
            r[j] = atomicAdd(&hist[b[j]], 1);
        }
    }
    __syncthreads();
    for (int i = t; i < NBKT; i += 256){
        int h = hist[i];
        int base = 0;
        if (h) base = atomicAdd(&bfill[i], h);
        gbase[i] = bptr[i] + base;
    }
    __syncthreads();
    #pragma unroll
    for (int j = 0; j < 8; ++j){
        int e = e0 + j*256 + t;
        if (e < E)
            pk[gbase[b[j]] + r[j]] =
                (unsigned)s[j] | ((unsigned)(d[j] & (BNODES-1)) << SRC_BITS);
    }
}

// per-bucket counting sort, one block per bucket. Local histogram + scan in LDS
// produce row_ptr for the bucket's 512 nodes AND the scatter offsets.
__global__ __launch_bounds__(1024) void sort_k(
        const unsigned* __restrict__ pk, const int* __restrict__ bptr,
        int* __restrict__ row_ptr, int* __restrict__ ssorted, int N, int E){
    __shared__ int hc[BNODES];      // histogram
    __shared__ int of[BNODES];      // scan -> exclusive offsets
    __shared__ int fi[BNODES];      // fill counters
    const int b  = blockIdx.x;
    const int n0 = b << BKT_SHIFT;
    const int t  = threadIdx.x;
    const int rbeg = bptr[b];
    const int rend = bptr[b+1];
    if (t < BNODES){ hc[t] = 0; fi[t] = 0; }
    __syncthreads();
    for (int e = rbeg + t; e < rend; e += 1024)
        atomicAdd(&hc[pk[e] >> SRC_BITS], 1);
    __syncthreads();
    if (t < BNODES) of[t] = hc[t];
    __syncthreads();
    for (int off = 1; off < BNODES; off <<= 1){
        int add = (t < BNODES && t >= off) ? of[t-off] : 0;
        __syncthreads();
        if (t < BNODES) of[t] += add;
        __syncthreads();
    }
    // of = inclusive; convert to exclusive and publish row_ptr
    if (t < BNODES){
        int excl = of[t] - hc[t];
        of[t] = excl;
        int node = n0 + t;
        if (node <= N) row_ptr[node] = rbeg + excl;   // node==N gets E (last bucket)
    }
    __syncthreads();
    for (int e = rbeg + t; e < rend; e += 1024){
        unsigned p = pk[e];
        int dl = (int)(p >> SRC_BITS);
        int pos = rbeg + of[dl] + atomicAdd(&fi[dl], 1);
        ssorted[pos] = (int)(p & SRC_MASK);
    }
}

// ---------------- conversions ----------------

__global__ void xconv_k(const float* __restrict__ x, unsigned short* __restrict__ xb, int n4){
    int i = blockIdx.x*256 + threadIdx.x;
    if (i < n4){
        const float4* p = (const float4*)x + i;
        float4 v = *p;
        unsigned short o0 = f2bf(v.x), o1 = f2bf(v.y), o2 = f2bf(v.z), o3 = f2bf(v.w);
        ((unsigned*)xb)[i*2]   = (unsigned)o0 | ((unsigned)o1 << 16);
        ((unsigned*)xb)[i*2+1] = (unsigned)o2 | ((unsigned)o3 << 16);
    }
}

// all three layers' weights -> combined transposed bf16 Wt[n][k] in one launch.
__global__ void prepw_all_k(const float* __restrict__ Ws0, const float* __restrict__ Wn0,
                            const float* __restrict__ Ws1, const float* __restrict__ Wn1,
                            const float* __restrict__ Ws2, const float* __restrict__ Wn2,
                            unsigned short* __restrict__ Wt0, unsigned short* __restrict__ Wt1,
                            unsigned short* __restrict__ Wt2){
    int i = blockIdx.x*256 + threadIdx.x;
    const float* Ws; const float* Wn; unsigned short* Wt; int D; int idx;
    if (i < 32768){       Ws=Ws0; Wn=Wn0; Wt=Wt0; D=128; idx=i; }
    else if (i < 65536){  Ws=Ws1; Wn=Wn1; Wt=Wt1; D=128; idx=i-32768; }
    else {                Ws=Ws2; Wn=Wn2; Wt=Wt2; D=47;  idx=i-65536; }
    int n = idx >> 7, k = idx & 127;
    float v = 0.f;
    if (n < D)        v = Ws[k*D + n];
    else if (n < 2*D) v = Wn[k*D + (n - D)];
    Wt[n*128 + k] = f2bf(v);
}

// ---------------- MFMA GEMM ----------------
// Block: 256 thr = 4 waves (2M x 2N of 64x64). Tile BM=128, BN=128 (cols of [Ws|Wn]).
// A staged in LDS via global_load_lds w/ XOR chunk swizzle; B fragments in registers.

__global__ __launch_bounds__(256) void gemm_mfma_k(
        const unsigned short* __restrict__ hb,   // [M][128] bf16
        const unsigned short* __restrict__ Wt,   // [Npad][128] bf16
        const float* __restrict__ bias,
        unsigned short* __restrict__ Y,          // [M][Dpad] bf16
        unsigned short* __restrict__ Z,          // [M][Dpad] bf16
        int M, int D, int Dpad){
    __shared__ char ldsA[128*256];               // 128 rows x 256B
    const int t = threadIdx.x;
    const int lane = t & 63;
    const int w = t >> 6;
    const int wm = w >> 1, wn = w & 1;
    const int tile = blockIdx.x * 128;
    const int cbase = blockIdx.y * 128;

    #pragma unroll
    for (int i = 0; i < 8; ++i){
        int chunkid = i*4 + w;
        int lin = chunkid*64 + lane;
        int row = lin >> 4;
        int cs  = lin & 15;
        int grow = tile + row; if (grow >= M) grow = M - 1;
        const char* src = (const char*)hb + (size_t)grow*256 + ((size_t)(cs ^ (row & 7)) << 4);
        __builtin_amdgcn_global_load_lds(
            (const __attribute__((address_space(1))) void*)src,
            (__attribute__((address_space(3))) void*)(ldsA + (size_t)chunkid*1024 + (size_t)lane*16),
            16, 0, 0);
    }

    short8 bfrag[4][4];
    {
        int ncol = cbase + wn*64;
        #pragma unroll
        for (int n = 0; n < 4; ++n){
            int wrow = ncol + n*16 + (lane & 15);
            const unsigned short* bp = Wt + (size_t)wrow*128 + ((lane >> 4) * 8);
            #pragma unroll
            for (int kk = 0; kk < 4; ++kk)
                bfrag[n][kk] = *(const short8*)(bp + kk*32);
        }
    }

    float4v acc[4][4];
    #pragma unroll
    for (int m = 0; m < 4; ++m)
        #pragma unroll
        for (int n = 0; n < 4; ++n)
            acc[m][n] = (float4v){0.f,0.f,0.f,0.f};

    __syncthreads();

    #pragma unroll
    for (int m = 0; m < 4; ++m){
        int r = wm*64 + m*16 + (lane & 15);
        #pragma unroll
        for (int kk = 0; kk < 4; ++kk){
            int c = kk*4 + (lane >> 4);
            short8 a = *(const short8*)(ldsA + (size_t)r*256 + ((size_t)(c ^ (r & 7)) << 4));
            #pragma unroll
            for (int n = 0; n < 4; ++n)
                acc[m][n] = __builtin_amdgcn_mfma_f32_16x16x32_bf16(a, bfrag[n][kk], acc[m][n], 0, 0, 0);
        }
    }

    #pragma unroll
    for (int m = 0; m < 4; ++m){
        #pragma unroll
        for (int n = 0; n < 4; ++n){
            int c = cbase + wn*64 + n*16 + (lane & 15);
            #pragma unroll
            for (int j = 0; j < 4; ++j){
                int r = tile + wm*64 + m*16 + (lane >> 4)*4 + j;
                if (r < M){
                    float v = acc[m][n][j];
                    if (c < D){
                        v += bias[c];
                        Y[(size_t)r*Dpad + c] = f2bf(v);
                    } else if (c < 2*D){
                        Z[(size_t)r*Dpad + (c - D)] = f2bf(v);
                    }
                }
            }
        }
    }
}

// ---------------- aggregation ----------------
// out = relu(Y + mean(Z[src])). One wave per node; quarter-wave (16 lanes) per edge,
// each lane loads uint4 (8 feats). 32 edges (8 loads/lane) in flight per batch.

__global__ __launch_bounds__(256) void agg128_k(
        const unsigned short* __restrict__ Yb, const unsigned short* __restrict__ Zb,
        const int* __restrict__ row_ptr, const int* __restrict__ ssorted,
        unsigned short* __restrict__ hout, int N){
    const int lane = threadIdx.x & 63;
    const int q   = lane >> 4;          // edge slot 0..3
    const int sub = lane & 15;          // feat group (8 feats = 16 B)
    const int node = blockIdx.x*4 + (threadIdx.x >> 6);
    if (node >= N) return;
    const int beg = __builtin_amdgcn_readfirstlane(row_ptr[node]);
    const int end = __builtin_amdgcn_readfirstlane(row_ptr[node+1]);
    const float inv = 1.0f / fmaxf((float)(end - beg), 1.0f);
    const char* zc = (const char*)Zb;
    const unsigned boff = (unsigned)(sub*16);
    f32x2 a0={0.f,0.f}, a1={0.f,0.f}, a2={0.f,0.f}, a3={0.f,0.f};
    for (int e = beg; e < end; e += 32){
        int s[8];
        #pragma unroll
        for (int j = 0; j < 8; ++j){
            int ei = e + 4*j + q;
            int ec = ei < end ? ei : end - 1;
            s[j] = ssorted[ec];
        }
        uint4 u[8];
        #pragma unroll
        for (int j = 0; j < 8; ++j)
            u[j] = *(const uint4*)(zc + ((unsigned)s[j]*256u + boff));
        #pragma unroll
        for (int j = 0; j < 8; ++j){
            if (e + 4*j + q < end){
                a0 += (f32x2){ bf_lo(u[j].x), bf_hi(u[j].x) };
                a1 += (f32x2){ bf_lo(u[j].y), bf_hi(u[j].y) };
                a2 += (f32x2){ bf_lo(u[j].z), bf_hi(u[j].z) };
                a3 += (f32x2){ bf_lo(u[j].w), bf_hi(u[j].w) };
            }
        }
    }
    // reduce across the 4 edge slots (lane bits 4,5)
    a0.x += __shfl_xor(a0.x,16,64); a0.x += __shfl_xor(a0.x,32,64);
    a0.y += __shfl_xor(a0.y,16,64); a0.y += __shfl_xor(a0.y,32,64);
    a1.x += __shfl_xor(a1.x,16,64); a1.x += __shfl_xor(a1.x,32,64);
    a1.y += __shfl_xor(a1.y,16,64); a1.y += __shfl_xor(a1.y,32,64);
    a2.x += __shfl_xor(a2.x,16,64); a2.x += __shfl_xor(a2.x,32,64);
    a2.y += __shfl_xor(a2.y,16,64); a2.y += __shfl_xor(a2.y,32,64);
    a3.x += __shfl_xor(a3.x,16,64); a3.x += __shfl_xor(a3.x,32,64);
    a3.y += __shfl_xor(a3.y,16,64); a3.y += __shfl_xor(a3.y,32,64);
    if (q == 0){
        uint4 yu = *(const uint4*)((const char*)Yb + (size_t)node*256 + sub*16);
        float r0 = fmaxf(bf_lo(yu.x) + a0.x*inv, 0.f);
        float r1 = fmaxf(bf_hi(yu.x) + a0.y*inv, 0.f);
        float r2 = fmaxf(bf_lo(yu.y) + a1.x*inv, 0.f);
        float r3 = fmaxf(bf_hi(yu.y) + a1.y*inv, 0.f);
        float r4 = fmaxf(bf_lo(yu.z) + a2.x*inv, 0.f);
        float r5 = fmaxf(bf_hi(yu.z) + a2.y*inv, 0.f);
        float r6 = fmaxf(bf_lo(yu.w) + a3.x*inv, 0.f);
        float r7 = fmaxf(bf_hi(yu.w) + a3.y*inv, 0.f);
        uint4 o;
        o.x = (unsigned)f2bf(r0) | ((unsigned)f2bf(r1) << 16);
        o.y = (unsigned)f2bf(r2) | ((unsigned)f2bf(r3) << 16);
        o.z = (unsigned)f2bf(r4) | ((unsigned)f2bf(r5) << 16);
        o.w = (unsigned)f2bf(r6) | ((unsigned)f2bf(r7) << 16);
        *(uint4*)((char*)hout + (size_t)node*256 + sub*16) = o;
    }
}

// final layer: D=47 (Dpad=48), f32 out, no relu. Quarter-wave per edge,
// 12 active lanes x 4 feats (uint2); 32 edges in flight per batch.
__global__ __launch_bounds__(256) void aggfin_k(
        const unsigned short* __restrict__ Yb, const unsigned short* __restrict__ Zb,
        const int* __restrict__ row_ptr, const int* __restrict__ ssorted,
        float* __restrict__ out, int N){
    const int lane = threadIdx.x & 63;
    const int q   = lane >> 4;          // edge slot 0..3
    const int sub = lane & 15;          // feat group, active if <12
    const int node = blockIdx.x*4 + (threadIdx.x >> 6);
    if (node >= N) return;
    const int beg = __builtin_amdgcn_readfirstlane(row_ptr[node]);
    const int end = __builtin_amdgcn_readfirstlane(row_ptr[node+1]);
    const float inv = 1.0f / fmaxf((float)(end - beg), 1.0f);
    const char* zc = (const char*)Zb;
    const bool act = (sub < 12);
    const unsigned boff = (unsigned)(sub*8);
    f32x2 acc0 = {0.f,0.f}, acc1 = {0.f,0.f};
    for (int e = beg; e < end; e += 32){
        int s[8];
        #pragma unroll
        for (int j = 0; j < 8; ++j){
            int ei = e + 4*j + q;
            int ec = ei < end ? ei : end - 1;
            s[j] = ssorted[ec];
        }
        #pragma unroll
        for (int j = 0; j < 8; ++j){
            if (act){
                uint2 u = *(const uint2*)(zc + ((unsigned)s[j]*96u + boff));
                if (e + 4*j + q < end){
                    acc0 += (f32x2){ bf_lo(u.x), bf_lo(u.y) };
                    acc1 += (f32x2){ bf_hi(u.x), bf_hi(u.y) };
                }
            }
        }
    }
    acc0.x += __shfl_xor(acc0.x, 16, 64); acc0.x += __shfl_xor(acc0.x, 32, 64);
    acc0.y += __shfl_xor(acc0.y, 16, 64); acc0.y += __shfl_xor(acc0.y, 32, 64);
    acc1.x += __shfl_xor(acc1.x, 16, 64); acc1.x += __shfl_xor(acc1.x, 32, 64);
    acc1.y += __shfl_xor(acc1.y, 16, 64); acc1.y += __shfl_xor(acc1.y, 32, 64);
    if (q == 0 && act){
        uint2 yu = *(const uint2*)((const char*)Yb + (size_t)node*96 + sub*8);
        float r0 = bf_lo(yu.x) + acc0.x*inv;
        float r1 = bf_hi(yu.x) + acc1.x*inv;
        float r2 = bf_lo(yu.y) + acc0.y*inv;
        float r3 = bf_hi(yu.y) + acc1.y*inv;
        int f = 4*sub;
        size_t o = (size_t)node*47 + f;
        out[o]   = r0;
        out[o+1] = r1;
        out[o+2] = r2;
        if (f + 3 < 47) out[o+3] = r3;
    }
}

// ---------------- launch ----------------

extern "C" void kernel_launch(void* const* d_in, const int* in_sizes, int n_in,
                              void* d_out, int out_size, void* d_ws, size_t ws_size,
                              hipStream_t stream){
    const float* x   = (const float*)d_in[0];
    const int*   src = (const int*)  d_in[1];
    const int*   dstv= (const int*)  d_in[2];
    const float* Ws0 = (const float*)d_in[3];
    const float* Wn0 = (const float*)d_in[4];
    const float* b0  = (const float*)d_in[5];
    const float* Ws1 = (const float*)d_in[6];
    const float* Wn1 = (const float*)d_in[7];
    const float* b1  = (const float*)d_in[8];
    const float* Ws2 = (const float*)d_in[9];
    const float* Wn2 = (const float*)d_in[10];
    const float* b2  = (const float*)d_in[11];
    float* out = (float*)d_out;
    const int N = NN, E = NE;

    char* w = (char*)d_ws;
    size_t off = 0;
    auto alloc = [&](size_t bytes)->char*{
        char* p = w + off; off += (bytes + 255) & ~(size_t)255; return p;
    };
    int*   bbuf    = (int*)  alloc((size_t)(2*NBKT)*4);     // bcnt | bfill, one memset
    int*   bcnt    = bbuf;
    int*   bfill   = bbuf + NBKT;
    int*   bptr    = (int*)  alloc((size_t)(NBKT+1)*4);
    int*   row_ptr = (int*)  alloc((size_t)(NN+1)*4);
    int*   ssorted = (int*)  alloc((size_t)E*4);
    unsigned* pk   = (unsigned*)alloc((size_t)E*4);
    unsigned short* xb  = (unsigned short*)alloc((size_t)NN*F*2);
    unsigned short* hA  = (unsigned short*)alloc((size_t)NN*F*2);
    unsigned short* hB  = (unsigned short*)alloc((size_t)NN*F*2);
    unsigned short* Yb  = (unsigned short*)alloc((size_t)NN*F*2);
    unsigned short* Zb  = (unsigned short*)alloc((size_t)NN*F*2);
    unsigned short* Wt0 = (unsigned short*)alloc((size_t)256*128*2);
    unsigned short* Wt1 = (unsigned short*)alloc((size_t)256*128*2);
    unsigned short* Wt2 = (unsigned short*)alloc((size_t)128*128*2);
    (void)ws_size; (void)n_in; (void)in_sizes; (void)out_size;

    const int GE = (E + 2047)/2048;

    hipMemsetAsync(bbuf, 0, (size_t)(2*NBKT)*4, stream);
    bhist_k   <<<GE, 256, 0, stream>>>(dstv, bcnt, E);
    bscan_k   <<<1, 256, 0, stream>>>(bcnt, bptr);
    bscatter_k<<<GE, 256, 0, stream>>>(src, dstv, bptr, bfill, pk, E);
    sort_k    <<<NBKT, 1024, 0, stream>>>(pk, bptr, row_ptr, ssorted, N, E);

    xconv_k<<<(N*F/4 + 255)/256, 256, 0, stream>>>(x, xb, N*F/4);
    prepw_all_k<<<320, 256, 0, stream>>>(Ws0, Wn0, Ws1, Wn1, Ws2, Wn2, Wt0, Wt1, Wt2);

    const int GM = (N + 127)/128;
    const int GA = (N + 3)/4;

    gemm_mfma_k<<<dim3(GM,2), 256, 0, stream>>>(xb, Wt0, b0, Yb, Zb, N, 128, 128);
    agg128_k   <<<GA, 256, 0, stream>>>(Yb, Zb, row_ptr, ssorted, hA, N);
    gemm_mfma_k<<<dim3(GM,2), 256, 0, stream>>>(hA, Wt1, b1, Yb, Zb, N, 128, 128);
    agg128_k   <<<GA, 256, 0, stream>>>(Yb, Zb, row_ptr, ssorted, hB, N);
    gemm_mfma_k<<<dim3(GM,1), 256, 0, stream>>>(hB, Wt2, b2, Yb, Zb, N, 47, 48);
    aggfin_k   <<<GA, 256, 0, stream>>>(Yb, Zb, row_ptr, ssorted, out, N);
}

// Round 10
// 375.286 us; speedup vs baseline: 3.0677x; 1.0357x over previous
//
#include <hip/hip_runtime.h>
#include <cstdint>
#include <cstddef>

static const int NN = 100000;
static const int NE = 1600000;
static const int F  = 128;       // K dim (feature width)
static const int BKT_SHIFT = 9;  // 512 nodes per bucket
static const int BNODES = 1 << BKT_SHIFT;
static const int NBKT = (NN + BNODES - 1) >> BKT_SHIFT;   // 196 (must be <= 256)
static const int PKCAP = 16384;  // per-bucket region capacity (avg 8192, +90 sigma)
static const int SRC_BITS = 17;  // 100000 < 2^17
static const unsigned SRC_MASK = (1u << SRC_BITS) - 1u;

typedef __attribute__((ext_vector_type(8))) short short8;
typedef __attribute__((ext_vector_type(4))) float float4v;
typedef __attribute__((ext_vector_type(2))) float f32x2;

static __device__ __forceinline__ unsigned f2bf(float f){
    unsigned u = __builtin_bit_cast(unsigned, f);
    return (u + 0x7FFFu + ((u >> 16) & 1u)) >> 16;
}
static __device__ __forceinline__ float bf_lo(unsigned u){
    return __builtin_bit_cast(float, u << 16);
}
static __device__ __forceinline__ float bf_hi(unsigned u){
    return __builtin_bit_cast(float, u & 0xFFFF0000u);
}

// ---------------- CSR build ----------------
// bucket-scatter packed (src | dlocal<<17) into FIXED per-bucket regions of pk[].
// bfill[] (zeroed each launch) both reserves slots and ends as the bucket count.
__global__ __launch_bounds__(256) void bscatter_k(
        const int* __restrict__ src, const int* __restrict__ dst,
        int* __restrict__ bfill, unsigned* __restrict__ pk, int E){
    __shared__ int hist[NBKT];
    __shared__ int gbase[NBKT];
    const int t = threadIdx.x;
    for (int i = t; i < NBKT; i += 256) hist[i] = 0;
    __syncthreads();
    const int e0 = blockIdx.x * 2048;
    int s[8], d[8], b[8], r[8];
    #pragma unroll
    for (int j = 0; j < 8; ++j){
        int e = e0 + j*256 + t;
        if (e < E){
            s[j] = src[e]; d[j] = dst[e];
            b[j] = d[j] >> BKT_SHIFT;
            r[j] = atomicAdd(&hist[b[j]], 1);
        }
    }
    __syncthreads();
    for (int i = t; i < NBKT; i += 256){
        int h = hist[i];
        int base = 0;
        if (h) base = atomicAdd(&bfill[i], h);
        gbase[i] = i*PKCAP + base;
    }
    __syncthreads();
    #pragma unroll
    for (int j = 0; j < 8; ++j){
        int e = e0 + j*256 + t;
        if (e < E)
            pk[gbase[b[j]] + r[j]] =
                (unsigned)s[j] | ((unsigned)(d[j] & (BNODES-1)) << SRC_BITS);
    }
}

// per-bucket counting sort, one block per bucket. Derives the global bucket
// prefix from a 196-entry LDS scan of bfill, emits row_ptr AND ssorted.
__global__ __launch_bounds__(1024) void sort_k(
        const unsigned* __restrict__ pk, const int* __restrict__ bfill,
        int* __restrict__ row_ptr, int* __restrict__ ssorted, int N){
    __shared__ int bs[256];         // bucket-count scan
    __shared__ int hc[BNODES];      // node histogram
    __shared__ int of[BNODES];      // exclusive offsets
    __shared__ int fi[BNODES];      // fill counters
    const int b = blockIdx.x;
    const int t = threadIdx.x;
    if (t < 256) bs[t] = (t < NBKT) ? bfill[t] : 0;
    if (t < BNODES){ hc[t] = 0; fi[t] = 0; }
    __syncthreads();
    for (int off = 1; off < 256; off <<= 1){
        int add = (t < 256 && t >= off) ? bs[t-off] : 0;
        __syncthreads();
        if (t < 256) bs[t] += add;
        __syncthreads();
    }
    const int cntb = bfill[b];
    const int rbeg = bs[b] - cntb;              // exclusive prefix of this bucket
    const unsigned* mypk = pk + (size_t)b * PKCAP;
    for (int i = t; i < cntb; i += 1024)
        atomicAdd(&hc[mypk[i] >> SRC_BITS], 1);
    __syncthreads();
    if (t < BNODES) of[t] = hc[t];
    __syncthreads();
    for (int off = 1; off < BNODES; off <<= 1){
        int add = (t < BNODES && t >= off) ? of[t-off] : 0;
        __syncthreads();
        if (t < BNODES) of[t] += add;
        __syncthreads();
    }
    if (t < BNODES){
        int excl = of[t] - hc[t];
        of[t] = excl;
        int node = (b << BKT_SHIFT) + t;
        if (node < N) row_ptr[node] = rbeg + excl;
    }
    if (b == 0 && t == 0) row_ptr[N] = NE;
    __syncthreads();
    for (int i = t; i < cntb; i += 1024){
        unsigned p = mypk[i];
        int dl = (int)(p >> SRC_BITS);
        int pos = rbeg + of[dl] + atomicAdd(&fi[dl], 1);
        ssorted[pos] = (int)(p & SRC_MASK);
    }
}

// ---------------- conversions ----------------

__global__ void xconv_k(const float* __restrict__ x, unsigned short* __restrict__ xb, int n8){
    int i = blockIdx.x*256 + threadIdx.x;
    if (i < n8){
        float4 v0 = ((const float4*)x)[i*2];
        float4 v1 = ((const float4*)x)[i*2+1];
        uint4 o;
        o.x = f2bf(v0.x) | (f2bf(v0.y) << 16);
        o.y = f2bf(v0.z) | (f2bf(v0.w) << 16);
        o.z = f2bf(v1.x) | (f2bf(v1.y) << 16);
        o.w = f2bf(v1.z) | (f2bf(v1.w) << 16);
        ((uint4*)xb)[i] = o;
    }
}

// all three layers' weights -> combined transposed bf16 Wt[n][k] in one launch.
__global__ void prepw_all_k(const float* __restrict__ Ws0, const float* __restrict__ Wn0,
                            const float* __restrict__ Ws1, const float* __restrict__ Wn1,
                            const float* __restrict__ Ws2, const float* __restrict__ Wn2,
                            unsigned short* __restrict__ Wt0, unsigned short* __restrict__ Wt1,
                            unsigned short* __restrict__ Wt2){
    int i = blockIdx.x*256 + threadIdx.x;
    const float* Ws; const float* Wn; unsigned short* Wt; int D; int idx;
    if (i < 32768){       Ws=Ws0; Wn=Wn0; Wt=Wt0; D=128; idx=i; }
    else if (i < 65536){  Ws=Ws1; Wn=Wn1; Wt=Wt1; D=128; idx=i-32768; }
    else {                Ws=Ws2; Wn=Wn2; Wt=Wt2; D=47;  idx=i-65536; }
    int n = idx >> 7, k = idx & 127;
    float v = 0.f;
    if (n < D)        v = Ws[k*D + n];
    else if (n < 2*D) v = Wn[k*D + (n - D)];
    Wt[n*128 + k] = (unsigned short)f2bf(v);
}

// ---------------- MFMA GEMM ----------------
// Block: 256 thr = 4 waves (2M x 2N of 64x64). Tile BM=128, BN=128 (cols of [Ws|Wn]).
// A staged in LDS via global_load_lds w/ XOR chunk swizzle; B fragments in registers.

__global__ __launch_bounds__(256) void gemm_mfma_k(
        const unsigned short* __restrict__ hb,   // [M][128] bf16
        const unsigned short* __restrict__ Wt,   // [Npad][128] bf16
        const float* __restrict__ bias,
        unsigned short* __restrict__ Y,          // [M][Dpad] bf16
        unsigned short* __restrict__ Z,          // [M][Dpad] bf16
        int M, int D, int Dpad){
    __shared__ char ldsA[128*256];               // 128 rows x 256B
    const int t = threadIdx.x;
    const int lane = t & 63;
    const int w = t >> 6;
    const int wm = w >> 1, wn = w & 1;
    const int tile = blockIdx.x * 128;
    const int cbase = blockIdx.y * 128;

    #pragma unroll
    for (int i = 0; i < 8; ++i){
        int chunkid = i*4 + w;
        int lin = chunkid*64 + lane;
        int row = lin >> 4;
        int cs  = lin & 15;
        int grow = tile + row; if (grow >= M) grow = M - 1;
        const char* src = (const char*)hb + (size_t)grow*256 + ((size_t)(cs ^ (row & 7)) << 4);
        __builtin_amdgcn_global_load_lds(
            (const __attribute__((address_space(1))) void*)src,
            (__attribute__((address_space(3))) void*)(ldsA + (size_t)chunkid*1024 + (size_t)lane*16),
            16, 0, 0);
    }

    short8 bfrag[4][4];
    {
        int ncol = cbase + wn*64;
        #pragma unroll
        for (int n = 0; n < 4; ++n){
            int wrow = ncol + n*16 + (lane & 15);
            const unsigned short* bp = Wt + (size_t)wrow*128 + ((lane >> 4) * 8);
            #pragma unroll
            for (int kk = 0; kk < 4; ++kk)
                bfrag[n][kk] = *(const short8*)(bp + kk*32);
        }
    }

    float4v acc[4][4];
    #pragma unroll
    for (int m = 0; m < 4; ++m)
        #pragma unroll
        for (int n = 0; n < 4; ++n)
            acc[m][n] = (float4v){0.f,0.f,0.f,0.f};

    __syncthreads();

    #pragma unroll
    for (int m = 0; m < 4; ++m){
        int r = wm*64 + m*16 + (lane & 15);
        #pragma unroll
        for (int kk = 0; kk < 4; ++kk){
            int c = kk*4 + (lane >> 4);
            short8 a = *(const short8*)(ldsA + (size_t)r*256 + ((size_t)(c ^ (r & 7)) << 4));
            #pragma unroll
            for (int n = 0; n < 4; ++n)
                acc[m][n] = __builtin_amdgcn_mfma_f32_16x16x32_bf16(a, bfrag[n][kk], acc[m][n], 0, 0, 0);
        }
    }

    #pragma unroll
    for (int m = 0; m < 4; ++m){
        #pragma unroll
        for (int n = 0; n < 4; ++n){
            int c = cbase + wn*64 + n*16 + (lane & 15);
            #pragma unroll
            for (int j = 0; j < 4; ++j){
                int r = tile + wm*64 + m*16 + (lane >> 4)*4 + j;
                if (r < M){
                    float v = acc[m][n][j];
                    if (c < D){
                        v += bias[c];
                        Y[(size_t)r*Dpad + c] = (unsigned short)f2bf(v);
                    } else if (c < 2*D){
                        Z[(size_t)r*Dpad + (c - D)] = (unsigned short)f2bf(v);
                    }
                }
            }
        }
    }
}

// ---------------- aggregation ----------------
// out = relu(Y + mean(Z[src])). One wave per node; quarter-wave (16 lanes) per edge,
// uint4 (8 feats) per lane. Wave caches its first 64 edge ids in registers (one
// coalesced load). NOTE: the shfl distributing the cache runs UNCONDITIONALLY by
// all 64 lanes (ds_bpermute returns undefined data from EXEC-inactive lanes);
// only the Z-row gather load and accumulate are predicated.

__global__ __launch_bounds__(256) void agg128_k(
        const unsigned short* __restrict__ Yb, const unsigned short* __restrict__ Zb,
        const int* __restrict__ row_ptr, const int* __restrict__ ssorted,
        unsigned short* __restrict__ hout, int N){
    const int lane = threadIdx.x & 63;
    const int q   = lane >> 4;          // edge slot 0..3
    const int sub = lane & 15;          // feat group (8 feats = 16 B)
    const int node = blockIdx.x*4 + (threadIdx.x >> 6);
    if (node >= N) return;
    const int beg = __builtin_amdgcn_readfirstlane(row_ptr[node]);
    const int end = __builtin_amdgcn_readfirstlane(row_ptr[node+1]);
    const float inv = 1.0f / fmaxf((float)(end - beg), 1.0f);
    const char* zc = (const char*)Zb;
    const unsigned boff = (unsigned)(sub*16);
    int ecache;
    { int ei0 = beg + lane; if (ei0 > NE-1) ei0 = NE-1; ecache = ssorted[ei0]; }
    f32x2 a0={0.f,0.f}, a1={0.f,0.f}, a2={0.f,0.f}, a3={0.f,0.f};
    for (int e = beg; e < end; e += 32){
        int rel0 = e - beg;
        int sidx[8];
        #pragma unroll
        for (int j = 0; j < 8; ++j){
            int rel = rel0 + 4*j + q;
            sidx[j] = __shfl(ecache, rel & 63, 64);   // all lanes execute
        }
        uint4 u[8];
        #pragma unroll
        for (int j = 0; j < 8; ++j){
            int ei = e + 4*j + q;
            if (ei < end){
                int rel = rel0 + 4*j + q;
                int s = (rel < 64) ? sidx[j] : ssorted[ei];
                u[j] = *(const uint4*)(zc + ((unsigned)s*256u + boff));
            }
        }
        #pragma unroll
        for (int j = 0; j < 8; ++j){
            if (e + 4*j + q < end){
                a0 += (f32x2){ bf_lo(u[j].x), bf_hi(u[j].x) };
                a1 += (f32x2){ bf_lo(u[j].y), bf_hi(u[j].y) };
                a2 += (f32x2){ bf_lo(u[j].z), bf_hi(u[j].z) };
                a3 += (f32x2){ bf_lo(u[j].w), bf_hi(u[j].w) };
            }
        }
    }
    // reduce across the 4 edge slots (lane bits 4,5)
    a0.x += __shfl_xor(a0.x,16,64); a0.x += __shfl_xor(a0.x,32,64);
    a0.y += __shfl_xor(a0.y,16,64); a0.y += __shfl_xor(a0.y,32,64);
    a1.x += __shfl_xor(a1.x,16,64); a1.x += __shfl_xor(a1.x,32,64);
    a1.y += __shfl_xor(a1.y,16,64); a1.y += __shfl_xor(a1.y,32,64);
    a2.x += __shfl_xor(a2.x,16,64); a2.x += __shfl_xor(a2.x,32,64);
    a2.y += __shfl_xor(a2.y,16,64); a2.y += __shfl_xor(a2.y,32,64);
    a3.x += __shfl_xor(a3.x,16,64); a3.x += __shfl_xor(a3.x,32,64);
    a3.y += __shfl_xor(a3.y,16,64); a3.y += __shfl_xor(a3.y,32,64);
    if (q == 0){
        uint4 yu = *(const uint4*)((const char*)Yb + (size_t)node*256 + sub*16);
        float r0 = fmaxf(bf_lo(yu.x) + a0.x*inv, 0.f);
        float r1 = fmaxf(bf_hi(yu.x) + a0.y*inv, 0.f);
        float r2 = fmaxf(bf_lo(yu.y) + a1.x*inv, 0.f);
        float r3 = fmaxf(bf_hi(yu.y) + a1.y*inv, 0.f);
        float r4 = fmaxf(bf_lo(yu.z) + a2.x*inv, 0.f);
        float r5 = fmaxf(bf_hi(yu.z) + a2.y*inv, 0.f);
        float r6 = fmaxf(bf_lo(yu.w) + a3.x*inv, 0.f);
        float r7 = fmaxf(bf_hi(yu.w) + a3.y*inv, 0.f);
        uint4 o;
        o.x = f2bf(r0) | (f2bf(r1) << 16);
        o.y = f2bf(r2) | (f2bf(r3) << 16);
        o.z = f2bf(r4) | (f2bf(r5) << 16);
        o.w = f2bf(r6) | (f2bf(r7) << 16);
        *(uint4*)((char*)hout + (size_t)node*256 + sub*16) = o;
    }
}

// final layer: D=47 (Dpad=48), f32 out, no relu. Quarter-wave per edge,
// 12 active lanes x 4 feats (uint2); unconditional shfl, predicated loads.
__global__ __launch_bounds__(256) void aggfin_k(
        const unsigned short* __restrict__ Yb, const unsigned short* __restrict__ Zb,
        const int* __restrict__ row_ptr, const int* __restrict__ ssorted,
        float* __restrict__ out, int N){
    const int lane = threadIdx.x & 63;
    const int q   = lane >> 4;          // edge slot 0..3
    const int sub = lane & 15;          // feat group, active if <12
    const int node = blockIdx.x*4 + (threadIdx.x >> 6);
    if (node >= N) return;
    const int beg = __builtin_amdgcn_readfirstlane(row_ptr[node]);
    const int end = __builtin_amdgcn_readfirstlane(row_ptr[node+1]);
    const float inv = 1.0f / fmaxf((float)(end - beg), 1.0f);
    const char* zc = (const char*)Zb;
    const bool act = (sub < 12);
    const unsigned boff = (unsigned)(sub*8);
    int ecache;
    { int ei0 = beg + lane; if (ei0 > NE-1) ei0 = NE-1; ecache = ssorted[ei0]; }
    f32x2 acc0 = {0.f,0.f}, acc1 = {0.f,0.f};
    for (int e = beg; e < end; e += 32){
        int rel0 = e - beg;
        int sidx[8];
        #pragma unroll
        for (int j = 0; j < 8; ++j){
            int rel = rel0 + 4*j + q;
            sidx[j] = __shfl(ecache, rel & 63, 64);   // all lanes execute
        }
        uint2 u[8];
        #pragma unroll
        for (int j = 0; j < 8; ++j){
            int ei = e + 4*j + q;
            if (act && ei < end){
                int rel = rel0 + 4*j + q;
                int s = (rel < 64) ? sidx[j] : ssorted[ei];
                u[j] = *(const uint2*)(zc + ((unsigned)s*96u + boff));
            }
        }
        #pragma unroll
        for (int j = 0; j < 8; ++j){
            if (act && e + 4*j + q < end){
                acc0 += (f32x2){ bf_lo(u[j].x), bf_lo(u[j].y) };
                acc1 += (f32x2){ bf_hi(u[j].x), bf_hi(u[j].y) };
            }
        }
    }
    acc0.x += __shfl_xor(acc0.x, 16, 64); acc0.x += __shfl_xor(acc0.x, 32, 64);
    acc0.y += __shfl_xor(acc0.y, 16, 64); acc0.y += __shfl_xor(acc0.y, 32, 64);
    acc1.x += __shfl_xor(acc1.x, 16, 64); acc1.x += __shfl_xor(acc1.x, 32, 64);
    acc1.y += __shfl_xor(acc1.y, 16, 64); acc1.y += __shfl_xor(acc1.y, 32, 64);
    if (q == 0 && act){
        uint2 yu = *(const uint2*)((const char*)Yb + (size_t)node*96 + sub*8);
        float r0 = bf_lo(yu.x) + acc0.x*inv;
        float r1 = bf_hi(yu.x) + acc1.x*inv;
        float r2 = bf_lo(yu.y) + acc0.y*inv;
        float r3 = bf_hi(yu.y) + acc1.y*inv;
        int f = 4*sub;
        size_t o = (size_t)node*47 + f;
        out[o]   = r0;
        out[o+1] = r1;
        out[o+2] = r2;
        if (f + 3 < 47) out[o+3] = r3;
    }
}

// ---------------- launch ----------------

extern "C" void kernel_launch(void* const* d_in, const int* in_sizes, int n_in,
                              void* d_out, int out_size, void* d_ws, size_t ws_size,
                              hipStream_t stream){
    const float* x   = (const float*)d_in[0];
    const int*   src = (const int*)  d_in[1];
    const int*   dstv= (const int*)  d_in[2];
    const float* Ws0 = (const float*)d_in[3];
    const float* Wn0 = (const float*)d_in[4];
    const float* b0  = (const float*)d_in[5];
    const float* Ws1 = (const float*)d_in[6];
    const float* Wn1 = (const float*)d_in[7];
    const float* b1  = (const float*)d_in[8];
    const float* Ws2 = (const float*)d_in[9];
    const float* Wn2 = (const float*)d_in[10];
    const float* b2  = (const float*)d_in[11];
    float* out = (float*)d_out;
    const int N = NN, E = NE;

    char* w = (char*)d_ws;
    size_t off = 0;
    auto alloc = [&](size_t bytes)->char*{
        char* p = w + off; off += (bytes + 255) & ~(size_t)255; return p;
    };
    int*   bfill   = (int*)  alloc((size_t)NBKT*4);
    int*   row_ptr = (int*)  alloc((size_t)(NN+1)*4);
    int*   ssorted = (int*)  alloc((size_t)E*4);
    unsigned* pk   = (unsigned*)alloc((size_t)NBKT*PKCAP*4);
    unsigned short* xb  = (unsigned short*)alloc((size_t)NN*F*2);
    unsigned short* hA  = (unsigned short*)alloc((size_t)NN*F*2);
    unsigned short* hB  = (unsigned short*)alloc((size_t)NN*F*2);
    unsigned short* Yb  = (unsigned short*)alloc((size_t)NN*F*2);
    unsigned short* Zb  = (unsigned short*)alloc((size_t)NN*F*2);
    unsigned short* Wt0 = (unsigned short*)alloc((size_t)256*128*2);
    unsigned short* Wt1 = (unsigned short*)alloc((size_t)256*128*2);
    unsigned short* Wt2 = (unsigned short*)alloc((size_t)128*128*2);
    (void)ws_size; (void)n_in; (void)in_sizes; (void)out_size;

    const int GE = (E + 2047)/2048;

    hipMemsetAsync(bfill, 0, (size_t)NBKT*4, stream);
    bscatter_k<<<GE, 256, 0, stream>>>(src, dstv, bfill, pk, E);
    sort_k    <<<NBKT, 1024, 0, stream>>>(pk, bfill, row_ptr, ssorted, N);

    xconv_k<<<(N*F/8 + 255)/256, 256, 0, stream>>>(x, xb, N*F/8);
    prepw_all_k<<<320, 256, 0, stream>>>(Ws0, Wn0, Ws1, Wn1, Ws2, Wn2, Wt0, Wt1, Wt2);

    const int GM = (N + 127)/128;
    const int GA = (N + 3)/4;

    gemm_mfma_k<<<dim3(GM,2), 256, 0, stream>>>(xb, Wt0, b0, Yb, Zb, N, 128, 128);
    agg128_k   <<<GA, 256, 0, stream>>>(Yb, Zb, row_ptr, ssorted, hA, N);
    gemm_mfma_k<<<dim3(GM,2), 256, 0, stream>>>(hA, Wt1, b1, Yb, Zb, N, 128, 128);
    agg128_k   <<<GA, 256, 0, stream>>>(Yb, Zb, row_ptr, ssorted, hB, N);
    gemm_mfma_k<<<dim3(GM,1), 256, 0, stream>>>(hB, Wt2, b2, Yb, Zb, N, 47, 48);
    aggfin_k   <<<GA, 256, 0, stream>>>(Yb, Zb, row_ptr, ssorted, out, N);
}

// Round 11
// 359.060 us; speedup vs baseline: 3.2064x; 1.0452x over previous
//
#include <hip/hip_runtime.h>
#include <cstdint>
#include <cstddef>

static const int NN = 100000;
static const int NE = 1600000;
static const int F  = 128;       // K dim (feature width)
static const int BKT_SHIFT = 9;  // 512 nodes per bucket
static const int BNODES = 1 << BKT_SHIFT;
static const int NBKT = (NN + BNODES - 1) >> BKT_SHIFT;   // 196 (must be <= 256)
static const int PKCAP = 16384;  // per-bucket region capacity (avg 8192, +90 sigma)
static const int SRC_BITS = 17;  // 100000 < 2^17
static const unsigned SRC_MASK = (1u << SRC_BITS) - 1u;

typedef __attribute__((ext_vector_type(8))) short short8;
typedef __attribute__((ext_vector_type(4))) float float4v;
typedef __attribute__((ext_vector_type(2))) float f32x2;

static __device__ __forceinline__ unsigned f2bf(float f){
    unsigned u = __builtin_bit_cast(unsigned, f);
    return (u + 0x7FFFu + ((u >> 16) & 1u)) >> 16;
}
static __device__ __forceinline__ float bf_lo(unsigned u){
    return __builtin_bit_cast(float, u << 16);
}
static __device__ __forceinline__ float bf_hi(unsigned u){
    return __builtin_bit_cast(float, u & 0xFFFF0000u);
}

// ---------------- CSR build ----------------
// bucket-scatter packed (src | dlocal<<17) into FIXED per-bucket regions of pk[].
// bfill[] (zeroed each launch) both reserves slots and ends as the bucket count.
__global__ __launch_bounds__(256) void bscatter_k(
        const int* __restrict__ src, const int* __restrict__ dst,
        int* __restrict__ bfill, unsigned* __restrict__ pk, int E){
    __shared__ int hist[NBKT];
    __shared__ int gbase[NBKT];
    const int t = threadIdx.x;
    for (int i = t; i < NBKT; i += 256) hist[i] = 0;
    __syncthreads();
    const int e0 = blockIdx.x * 2048;
    int s[8], d[8], b[8], r[8];
    #pragma unroll
    for (int j = 0; j < 8; ++j){
        int e = e0 + j*256 + t;
        if (e < E){
            s[j] = src[e]; d[j] = dst[e];
            b[j] = d[j] >> BKT_SHIFT;
            r[j] = atomicAdd(&hist[b[j]], 1);
        }
    }
    __syncthreads();
    for (int i = t; i < NBKT; i += 256){
        int h = hist[i];
        int base = 0;
        if (h) base = atomicAdd(&bfill[i], h);
        gbase[i] = i*PKCAP + base;
    }
    __syncthreads();
    #pragma unroll
    for (int j = 0; j < 8; ++j){
        int e = e0 + j*256 + t;
        if (e < E)
            pk[gbase[b[j]] + r[j]] =
                (unsigned)s[j] | ((unsigned)(d[j] & (BNODES-1)) << SRC_BITS);
    }
}

// per-bucket counting sort, one block per bucket. Derives the global bucket
// prefix from a 196-entry LDS scan of bfill, emits row_ptr AND ssorted.
__global__ __launch_bounds__(1024) void sort_k(
        const unsigned* __restrict__ pk, const int* __restrict__ bfill,
        int* __restrict__ row_ptr, int* __restrict__ ssorted, int N){
    __shared__ int bs[256];         // bucket-count scan
    __shared__ int hc[BNODES];      // node histogram
    __shared__ int of[BNODES];      // exclusive offsets
    __shared__ int fi[BNODES];      // fill counters
    const int b = blockIdx.x;
    const int t = threadIdx.x;
    if (t < 256) bs[t] = (t < NBKT) ? bfill[t] : 0;
    if (t < BNODES){ hc[t] = 0; fi[t] = 0; }
    __syncthreads();
    for (int off = 1; off < 256; off <<= 1){
        int add = (t < 256 && t >= off) ? bs[t-off] : 0;
        __syncthreads();
        if (t < 256) bs[t] += add;
        __syncthreads();
    }
    const int cntb = bfill[b];
    const int rbeg = bs[b] - cntb;              // exclusive prefix of this bucket
    const unsigned* mypk = pk + (size_t)b * PKCAP;
    for (int i = t; i < cntb; i += 1024)
        atomicAdd(&hc[mypk[i] >> SRC_BITS], 1);
    __syncthreads();
    if (t < BNODES) of[t] = hc[t];
    __syncthreads();
    for (int off = 1; off < BNODES; off <<= 1){
        int add = (t < BNODES && t >= off) ? of[t-off] : 0;
        __syncthreads();
        if (t < BNODES) of[t] += add;
        __syncthreads();
    }
    if (t < BNODES){
        int excl = of[t] - hc[t];
        of[t] = excl;
        int node = (b << BKT_SHIFT) + t;
        if (node < N) row_ptr[node] = rbeg + excl;
    }
    if (b == 0 && t == 0) row_ptr[N] = NE;
    __syncthreads();
    for (int i = t; i < cntb; i += 1024){
        unsigned p = mypk[i];
        int dl = (int)(p >> SRC_BITS);
        int pos = rbeg + of[dl] + atomicAdd(&fi[dl], 1);
        ssorted[pos] = (int)(p & SRC_MASK);
    }
}

// ---------------- conversions ----------------

__global__ void xconv_k(const float* __restrict__ x, unsigned short* __restrict__ xb, int n8){
    int i = blockIdx.x*256 + threadIdx.x;
    if (i < n8){
        float4 v0 = ((const float4*)x)[i*2];
        float4 v1 = ((const float4*)x)[i*2+1];
        uint4 o;
        o.x = f2bf(v0.x) | (f2bf(v0.y) << 16);
        o.y = f2bf(v0.z) | (f2bf(v0.w) << 16);
        o.z = f2bf(v1.x) | (f2bf(v1.y) << 16);
        o.w = f2bf(v1.z) | (f2bf(v1.w) << 16);
        ((uint4*)xb)[i] = o;
    }
}

// all three layers' weights -> combined transposed bf16 Wt[n][k] in one launch.
__global__ void prepw_all_k(const float* __restrict__ Ws0, const float* __restrict__ Wn0,
                            const float* __restrict__ Ws1, const float* __restrict__ Wn1,
                            const float* __restrict__ Ws2, const float* __restrict__ Wn2,
                            unsigned short* __restrict__ Wt0, unsigned short* __restrict__ Wt1,
                            unsigned short* __restrict__ Wt2){
    int i = blockIdx.x*256 + threadIdx.x;
    const float* Ws; const float* Wn; unsigned short* Wt; int D; int idx;
    if (i < 32768){       Ws=Ws0; Wn=Wn0; Wt=Wt0; D=128; idx=i; }
    else if (i < 65536){  Ws=Ws1; Wn=Wn1; Wt=Wt1; D=128; idx=i-32768; }
    else {                Ws=Ws2; Wn=Wn2; Wt=Wt2; D=47;  idx=i-65536; }
    int n = idx >> 7, k = idx & 127;
    float v = 0.f;
    if (n < D)        v = Ws[k*D + n];
    else if (n < 2*D) v = Wn[k*D + (n - D)];
    Wt[n*128 + k] = (unsigned short)f2bf(v);
}

// ---------------- MFMA GEMM ----------------
// Block: 256 thr = 4 waves (2M x 2N of 64x64). Tile BM=128, BN=128 (cols of [Ws|Wn]).
// A staged in LDS via global_load_lds w/ XOR chunk swizzle; B fragments in registers.

__global__ __launch_bounds__(256) void gemm_mfma_k(
        const unsigned short* __restrict__ hb,   // [M][128] bf16
        const unsigned short* __restrict__ Wt,   // [Npad][128] bf16
        const float* __restrict__ bias,
        unsigned short* __restrict__ Y,          // [M][Dpad] bf16
        unsigned short* __restrict__ Z,          // [M][Dpad] bf16
        int M, int D, int Dpad){
    __shared__ char ldsA[128*256];               // 128 rows x 256B
    const int t = threadIdx.x;
    const int lane = t & 63;
    const int w = t >> 6;
    const int wm = w >> 1, wn = w & 1;
    const int tile = blockIdx.x * 128;
    const int cbase = blockIdx.y * 128;

    #pragma unroll
    for (int i = 0; i < 8; ++i){
        int chunkid = i*4 + w;
        int lin = chunkid*64 + lane;
        int row = lin >> 4;
        int cs  = lin & 15;
        int grow = tile + row; if (grow >= M) grow = M - 1;
        const char* src = (const char*)hb + (size_t)grow*256 + ((size_t)(cs ^ (row & 7)) << 4);
        __builtin_amdgcn_global_load_lds(
            (const __attribute__((address_space(1))) void*)src,
            (__attribute__((address_space(3))) void*)(ldsA + (size_t)chunkid*1024 + (size_t)lane*16),
            16, 0, 0);
    }

    short8 bfrag[4][4];
    {
        int ncol = cbase + wn*64;
        #pragma unroll
        for (int n = 0; n < 4; ++n){
            int wrow = ncol + n*16 + (lane & 15);
            const unsigned short* bp = Wt + (size_t)wrow*128 + ((lane >> 4) * 8);
            #pragma unroll
            for (int kk = 0; kk < 4; ++kk)
                bfrag[n][kk] = *(const short8*)(bp + kk*32);
        }
    }

    float4v acc[4][4];
    #pragma unroll
    for (int m = 0; m < 4; ++m)
        #pragma unroll
        for (int n = 0; n < 4; ++n)
            acc[m][n] = (float4v){0.f,0.f,0.f,0.f};

    __syncthreads();

    #pragma unroll
    for (int m = 0; m < 4; ++m){
        int r = wm*64 + m*16 + (lane & 15);
        #pragma unroll
        for (int kk = 0; kk < 4; ++kk){
            int c = kk*4 + (lane >> 4);
            short8 a = *(const short8*)(ldsA + (size_t)r*256 + ((size_t)(c ^ (r & 7)) << 4));
            #pragma unroll
            for (int n = 0; n < 4; ++n)
                acc[m][n] = __builtin_amdgcn_mfma_f32_16x16x32_bf16(a, bfrag[n][kk], acc[m][n], 0, 0, 0);
        }
    }

    #pragma unroll
    for (int m = 0; m < 4; ++m){
        #pragma unroll
        for (int n = 0; n < 4; ++n){
            int c = cbase + wn*64 + n*16 + (lane & 15);
            #pragma unroll
            for (int j = 0; j < 4; ++j){
                int r = tile + wm*64 + m*16 + (lane >> 4)*4 + j;
                if (r < M){
                    float v = acc[m][n][j];
                    if (c < D){
                        v += bias[c];
                        Y[(size_t)r*Dpad + c] = (unsigned short)f2bf(v);
                    } else if (c < 2*D){
                        Z[(size_t)r*Dpad + (c - D)] = (unsigned short)f2bf(v);
                    }
                }
            }
        }
    }
}

// ---------------- aggregation ----------------
// out = relu(Y + mean(Z[src])). One wave per node; quarter-wave (16 lanes) per edge,
// uint4 (8 feats) per lane, 32 edges per batch. Index loads unconditional-clamped
// (broadcast, cache-hit); Z-row gather predicated on ei < end (no shfl, lean VGPR).

__global__ __launch_bounds__(256) void agg128_k(
        const unsigned short* __restrict__ Yb, const unsigned short* __restrict__ Zb,
        const int* __restrict__ row_ptr, const int* __restrict__ ssorted,
        unsigned short* __restrict__ hout, int N){
    const int lane = threadIdx.x & 63;
    const int q   = lane >> 4;          // edge slot 0..3
    const int sub = lane & 15;          // feat group (8 feats = 16 B)
    const int node = blockIdx.x*4 + (threadIdx.x >> 6);
    if (node >= N) return;
    const int beg = __builtin_amdgcn_readfirstlane(row_ptr[node]);
    const int end = __builtin_amdgcn_readfirstlane(row_ptr[node+1]);
    const float inv = 1.0f / fmaxf((float)(end - beg), 1.0f);
    const char* zc = (const char*)Zb;
    const unsigned boff = (unsigned)(sub*16);
    f32x2 a0={0.f,0.f}, a1={0.f,0.f}, a2={0.f,0.f}, a3={0.f,0.f};
    for (int e = beg; e < end; e += 32){
        int s[8];
        #pragma unroll
        for (int j = 0; j < 8; ++j){
            int ei = e + 4*j + q;
            int ec = ei < end ? ei : end - 1;
            s[j] = ssorted[ec];
        }
        uint4 u[8];
        #pragma unroll
        for (int j = 0; j < 8; ++j){
            int ei = e + 4*j + q;
            if (ei < end)
                u[j] = *(const uint4*)(zc + ((unsigned)s[j]*256u + boff));
        }
        #pragma unroll
        for (int j = 0; j < 8; ++j){
            if (e + 4*j + q < end){
                a0 += (f32x2){ bf_lo(u[j].x), bf_hi(u[j].x) };
                a1 += (f32x2){ bf_lo(u[j].y), bf_hi(u[j].y) };
                a2 += (f32x2){ bf_lo(u[j].z), bf_hi(u[j].z) };
                a3 += (f32x2){ bf_lo(u[j].w), bf_hi(u[j].w) };
            }
        }
    }
    // reduce across the 4 edge slots (lane bits 4,5)
    a0.x += __shfl_xor(a0.x,16,64); a0.x += __shfl_xor(a0.x,32,64);
    a0.y += __shfl_xor(a0.y,16,64); a0.y += __shfl_xor(a0.y,32,64);
    a1.x += __shfl_xor(a1.x,16,64); a1.x += __shfl_xor(a1.x,32,64);
    a1.y += __shfl_xor(a1.y,16,64); a1.y += __shfl_xor(a1.y,32,64);
    a2.x += __shfl_xor(a2.x,16,64); a2.x += __shfl_xor(a2.x,32,64);
    a2.y += __shfl_xor(a2.y,16,64); a2.y += __shfl_xor(a2.y,32,64);
    a3.x += __shfl_xor(a3.x,16,64); a3.x += __shfl_xor(a3.x,32,64);
    a3.y += __shfl_xor(a3.y,16,64); a3.y += __shfl_xor(a3.y,32,64);
    if (q == 0){
        uint4 yu = *(const uint4*)((const char*)Yb + (size_t)node*256 + sub*16);
        float r0 = fmaxf(bf_lo(yu.x) + a0.x*inv, 0.f);
        float r1 = fmaxf(bf_hi(yu.x) + a0.y*inv, 0.f);
        float r2 = fmaxf(bf_lo(yu.y) + a1.x*inv, 0.f);
        float r3 = fmaxf(bf_hi(yu.y) + a1.y*inv, 0.f);
        float r4 = fmaxf(bf_lo(yu.z) + a2.x*inv, 0.f);
        float r5 = fmaxf(bf_hi(yu.z) + a2.y*inv, 0.f);
        float r6 = fmaxf(bf_lo(yu.w) + a3.x*inv, 0.f);
        float r7 = fmaxf(bf_hi(yu.w) + a3.y*inv, 0.f);
        uint4 o;
        o.x = f2bf(r0) | (f2bf(r1) << 16);
        o.y = f2bf(r2) | (f2bf(r3) << 16);
        o.z = f2bf(r4) | (f2bf(r5) << 16);
        o.w = f2bf(r6) | (f2bf(r7) << 16);
        *(uint4*)((char*)hout + (size_t)node*256 + sub*16) = o;
    }
}

// final layer: D=47 (Dpad=48), f32 out, no relu. Quarter-wave per edge,
// 12 active lanes x 4 feats (uint2); clamped index loads, predicated gathers.
__global__ __launch_bounds__(256) void aggfin_k(
        const unsigned short* __restrict__ Yb, const unsigned short* __restrict__ Zb,
        const int* __restrict__ row_ptr, const int* __restrict__ ssorted,
        float* __restrict__ out, int N){
    const int lane = threadIdx.x & 63;
    const int q   = lane >> 4;          // edge slot 0..3
    const int sub = lane & 15;          // feat group, active if <12
    const int node = blockIdx.x*4 + (threadIdx.x >> 6);
    if (node >= N) return;
    const int beg = __builtin_amdgcn_readfirstlane(row_ptr[node]);
    const int end = __builtin_amdgcn_readfirstlane(row_ptr[node+1]);
    const float inv = 1.0f / fmaxf((float)(end - beg), 1.0f);
    const char* zc = (const char*)Zb;
    const bool act = (sub < 12);
    const unsigned boff = (unsigned)(sub*8);
    f32x2 acc0 = {0.f,0.f}, acc1 = {0.f,0.f};
    for (int e = beg; e < end; e += 32){
        int s[8];
        #pragma unroll
        for (int j = 0; j < 8; ++j){
            int ei = e + 4*j + q;
            int ec = ei < end ? ei : end - 1;
            s[j] = ssorted[ec];
        }
        uint2 u[8];
        #pragma unroll
        for (int j = 0; j < 8; ++j){
            int ei = e + 4*j + q;
            if (act && ei < end)
                u[j] = *(const uint2*)(zc + ((unsigned)s[j]*96u + boff));
        }
        #pragma unroll
        for (int j = 0; j < 8; ++j){
            if (act && e + 4*j + q < end){
                acc0 += (f32x2){ bf_lo(u[j].x), bf_lo(u[j].y) };
                acc1 += (f32x2){ bf_hi(u[j].x), bf_hi(u[j].y) };
            }
        }
    }
    acc0.x += __shfl_xor(acc0.x, 16, 64); acc0.x += __shfl_xor(acc0.x, 32, 64);
    acc0.y += __shfl_xor(acc0.y, 16, 64); acc0.y += __shfl_xor(acc0.y, 32, 64);
    acc1.x += __shfl_xor(acc1.x, 16, 64); acc1.x += __shfl_xor(acc1.x, 32, 64);
    acc1.y += __shfl_xor(acc1.y, 16, 64); acc1.y += __shfl_xor(acc1.y, 32, 64);
    if (q == 0 && act){
        uint2 yu = *(const uint2*)((const char*)Yb + (size_t)node*96 + sub*8);
        float r0 = bf_lo(yu.x) + acc0.x*inv;
        float r1 = bf_hi(yu.x) + acc1.x*inv;
        float r2 = bf_lo(yu.y) + acc0.y*inv;
        float r3 = bf_hi(yu.y) + acc1.y*inv;
        int f = 4*sub;
        size_t o = (size_t)node*47 + f;
        out[o]   = r0;
        out[o+1] = r1;
        out[o+2] = r2;
        if (f + 3 < 47) out[o+3] = r3;
    }
}

// ---------------- launch ----------------

extern "C" void kernel_launch(void* const* d_in, const int* in_sizes, int n_in,
                              void* d_out, int out_size, void* d_ws, size_t ws_size,
                              hipStream_t stream){
    const float* x   = (const float*)d_in[0];
    const int*   src = (const int*)  d_in[1];
    const int*   dstv= (const int*)  d_in[2];
    const float* Ws0 = (const float*)d_in[3];
    const float* Wn0 = (const float*)d_in[4];
    const float* b0  = (const float*)d_in[5];
    const float* Ws1 = (const float*)d_in[6];
    const float* Wn1 = (const float*)d_in[7];
    const float* b1  = (const float*)d_in[8];
    const float* Ws2 = (const float*)d_in[9];
    const float* Wn2 = (const float*)d_in[10];
    const float* b2  = (const float*)d_in[11];
    float* out = (float*)d_out;
    const int N = NN, E = NE;

    char* w = (char*)d_ws;
    size_t off = 0;
    auto alloc = [&](size_t bytes)->char*{
        char* p = w + off; off += (bytes + 255) & ~(size_t)255; return p;
    };
    int*   bfill   = (int*)  alloc((size_t)NBKT*4);
    int*   row_ptr = (int*)  alloc((size_t)(NN+1)*4);
    int*   ssorted = (int*)  alloc((size_t)E*4);
    unsigned* pk   = (unsigned*)alloc((size_t)NBKT*PKCAP*4);
    unsigned short* xb  = (unsigned short*)alloc((size_t)NN*F*2);
    unsigned short* hA  = (unsigned short*)alloc((size_t)NN*F*2);
    unsigned short* hB  = (unsigned short*)alloc((size_t)NN*F*2);
    unsigned short* Yb  = (unsigned short*)alloc((size_t)NN*F*2);
    unsigned short* Zb  = (unsigned short*)alloc((size_t)NN*F*2);
    unsigned short* Wt0 = (unsigned short*)alloc((size_t)256*128*2);
    unsigned short* Wt1 = (unsigned short*)alloc((size_t)256*128*2);
    unsigned short* Wt2 = (unsigned short*)alloc((size_t)128*128*2);
    (void)ws_size; (void)n_in; (void)in_sizes; (void)out_size;

    const int GE = (E + 2047)/2048;

    hipMemsetAsync(bfill, 0, (size_t)NBKT*4, stream);
    bscatter_k<<<GE, 256, 0, stream>>>(src, dstv, bfill, pk, E);
    sort_k    <<<NBKT, 1024, 0, stream>>>(pk, bfill, row_ptr, ssorted, N);

    xconv_k<<<(N*F/8 + 255)/256, 256, 0, stream>>>(x, xb, N*F/8);
    prepw_all_k<<<320, 256, 0, stream>>>(Ws0, Wn0, Ws1, Wn1, Ws2, Wn2, Wt0, Wt1, Wt2);

    const int GM = (N + 127)/128;
    const int GA = (N + 3)/4;

    gemm_mfma_k<<<dim3(GM,2), 256, 0, stream>>>(xb, Wt0, b0, Yb, Zb, N, 128, 128);
    agg128_k   <<<GA, 256, 0, stream>>>(Yb, Zb, row_ptr, ssorted, hA, N);
    gemm_mfma_k<<<dim3(GM,2), 256, 0, stream>>>(hA, Wt1, b1, Yb, Zb, N, 128, 128);
    agg128_k   <<<GA, 256, 0, stream>>>(Yb, Zb, row_ptr, ssorted, hB, N);
    gemm_mfma_k<<<dim3(GM,1), 256, 0, stream>>>(hB, Wt2, b2, Yb, Zb, N, 47, 48);
    aggfin_k   <<<GA, 256, 0, stream>>>(Yb, Zb, row_ptr, ssorted, out, N);
}